// Round 8
// baseline (158749.438 us; speedup 1.0000x reference)
//
#include <hip/hip_runtime.h>
#include <math.h>

#define NBLK 256
#define NTHR 512

constexpr float EPSF = 1e-9f;
constexpr float LOG2PIF = 1.8378770664093453f;

// ---- workspace layout (float offsets) ----
constexpr size_t OFF_CNT  = 0;
constexpr size_t OFF_GEN  = 32;
constexpr size_t OFF_PART = 128;
constexpr size_t WENC = 4096;                        // [1024][576]
constexpr size_t BENC = WENC + (size_t)1024 * 576;   // [1024]
constexpr size_t WDEC = BENC + 1024;                 // [1024][512]
constexpr size_t BDEC = WDEC + (size_t)1024 * 512;   // [1024]
constexpr size_t HBUF = BDEC + 1024;                 // [2][512][256]
constexpr size_t CBUF = HBUF + (size_t)2 * 512 * 256;
constexpr size_t XIMP = CBUF + (size_t)2 * 512 * 256; // [2][512][64]
constexpr size_t WS_NEED = XIMP + (size_t)2 * 512 * 64;

constexpr size_t SZ  = (size_t)512 * 256;
constexpr size_t SZX = (size_t)512 * 64;

__device__ __forceinline__ float sigm_(float x) { return 1.f / (1.f + expf(-x)); }
__device__ __forceinline__ float softplus_(float x) { return x > 20.f ? x : log1pf(expf(x)); }

// PROVEN grid barrier (r1: 20.9ms PASS, r2: 18.2ms PASS, r7: PASS) — verbatim.
__device__ __forceinline__ void gbar(float* ws) {
  __syncthreads();
  if (threadIdx.x == 0) {
    __threadfence();
    unsigned* cnt = (unsigned*)(ws + OFF_CNT);
    unsigned* gen = (unsigned*)(ws + OFF_GEN);
    unsigned g = __hip_atomic_load(gen, __ATOMIC_RELAXED, __HIP_MEMORY_SCOPE_AGENT);
    unsigned a = __hip_atomic_fetch_add(cnt, 1u, __ATOMIC_ACQ_REL, __HIP_MEMORY_SCOPE_AGENT);
    if (a == NBLK - 1) {
      __hip_atomic_store(cnt, 0u, __ATOMIC_RELAXED, __HIP_MEMORY_SCOPE_AGENT);
      __hip_atomic_store(gen, g + 1u, __ATOMIC_RELEASE, __HIP_MEMORY_SCOPE_AGENT);
    } else {
      while (__hip_atomic_load(gen, __ATOMIC_RELAXED, __HIP_MEMORY_SCOPE_AGENT) == g) {
        __builtin_amdgcn_s_sleep(2);
      }
    }
    __threadfence();
  }
  __syncthreads();
}

__global__ void vader_init(
    const float* __restrict__ eWih, const float* __restrict__ ebih,
    const float* __restrict__ eWhh, const float* __restrict__ ebhh,
    const float* __restrict__ eWch, const float* __restrict__ ebch,
    const float* __restrict__ dbih, const float* __restrict__ dWhh,
    const float* __restrict__ dbhh, const float* __restrict__ dWch,
    const float* __restrict__ dbch, float* __restrict__ ws) {
  const int i0 = blockIdx.x * blockDim.x + threadIdx.x;
  const int stride = gridDim.x * blockDim.x;
  for (int i = i0; i < 4096; i += stride) ws[i] = 0.f;
  for (int i = i0; i < 512 * 256; i += stride) {
    ws[HBUF + i] = 0.f;
    ws[CBUF + i] = 0.f;
  }
  for (int i = i0; i < 1024 * 576; i += stride) {
    int n = i / 576, k = i - n * 576;
    float v;
    if (k < 64)       v = eWih[n * 64 + k];
    else if (k < 320) v = eWhh[n * 256 + (k - 64)];
    else {
      int j = k - 320;
      if (n < 512)      v = eWch[n * 256 + j];
      else if (n < 768) v = 0.f;
      else              v = eWch[(n - 256) * 256 + j];
    }
    ws[WENC + i] = v;
  }
  for (int i = i0; i < 1024 * 512; i += stride) {
    int n = i >> 9, k = i & 511;
    float v;
    if (k < 256) v = dWhh[n * 256 + k];
    else {
      int j = k - 256;
      if (n < 512)      v = dWch[n * 256 + j];
      else if (n < 768) v = 0.f;
      else              v = dWch[(n - 256) * 256 + j];
    }
    ws[WDEC + i] = v;
  }
  for (int i = i0; i < 1024; i += stride) {
    float bce = (i < 512) ? ebch[i] : ((i < 768) ? 0.f : ebch[i - 256]);
    ws[BENC + i] = ebih[i] + ebhh[i] + bce;
    float bcd = (i < 512) ? dbch[i] : ((i < 768) ? 0.f : dbch[i - 256]);
    ws[BDEC + i] = dbih[i] + dbhh[i] + bcd;
  }
}

// min-waves-per-EU = 1: LDS already limits to 1 block/CU; declaring 2 capped
// the allocator at 128 VGPRs and spilled the 18-float4 staging batch to
// scratch (HBM) — 487 GB/dispatch in r4/r7. (512,1) => 256-VGPR budget.
__global__ __launch_bounds__(NTHR, 1) void vader_main(
    const float* __restrict__ X, const float* __restrict__ MM, const float* __restrict__ NZ,
    const float* __restrict__ Wimp,
    const float* __restrict__ aeW, const float* __restrict__ aeb,
    const float* __restrict__ adW, const float* __restrict__ adb,
    const float* __restrict__ muW, const float* __restrict__ mub,
    const float* __restrict__ stW, const float* __restrict__ stb,
    const float* __restrict__ oW, const float* __restrict__ ob,
    const float* __restrict__ mcu, const float* __restrict__ vcu, const float* __restrict__ pcu,
    float* __restrict__ ws, float* __restrict__ out) {
  const int bid = blockIdx.x, tid = threadIdx.x;
  const int mi = bid & 7, hi = bid >> 3;
  const int m_base = mi << 6;
  const int hbase = hi << 3;
  const int b0 = bid << 1;

  // ---- LDS ----
  __shared__ float In_s[2][64][65];              // stride 65: b32 reads 2-way = free
  __shared__ __align__(16) float W_s[32][576];   // 73.7 KB resident gate-weight slice
  __shared__ __align__(16) char u1_raw[17408];   // enc: WimpT | dec: Wo_s + Xm/Mm
  __shared__ __align__(16) char u2_raw[8192];    // GateS | heads arrays | red_s
  __shared__ float C_s[64][9];
  __shared__ float Xrow_s[2][64];
  __shared__ float lat_s[2][3];
  __shared__ float tot_s[5];

  float (*WimpT_s)[68] = (float(*)[68])u1_raw;                 // [64][68]
  float (*Wo_s)[260]   = (float(*)[260])u1_raw;                // [8][260]
  float (*Xm_s)[12]    = (float(*)[12])(u1_raw + 8320);        // [64][12]
  float (*Mm_s)[12]    = (float(*)[12])(u1_raw + 8320 + 3072); // [64][12]
  float* GateS         = (float*)u2_raw;                        // [4][64][8]
  float (*Hrow_s)[256] = (float(*)[256])u2_raw;
  float (*cc_s)[256]   = (float(*)[256])(u2_raw + 2048);
  float (*mu_s)[32]    = (float(*)[32])(u2_raw + 4096);
  float (*std_s)[32]   = (float(*)[32])(u2_raw + 4352);
  float (*z_s)[32]     = (float(*)[32])(u2_raw + 4608);
  float* red_s         = (float*)u2_raw;                        // [512] final only

  float* hbuf = ws + HBUF;
  float* cbuf = ws + CBUF;
  float* ximp = ws + XIMP;
  float* part = ws + OFF_PART;

  // gates mapping: thread = (row mR, col-group nG of 4 gate-cols)
  const int mR = tid & 63, nG = tid >> 6;
  const int gate = nG >> 1, hq = (nG & 1) << 2;
  const int wrow = (gate << 3) + hq;
  const int st_r = tid >> 3, st_c = tid & 7;     // staging: row st_r, 8 floats @ col st_c*8
  const int um = tid >> 3, uh = tid & 7;
  const bool mse_blk = (hi < 8);

  const float* hb0 = hbuf + (size_t)(m_base + st_r) * 256 + (st_c << 3);
  const float* cb0 = cbuf + (size_t)(m_base + st_r) * 256 + (st_c << 3);
  const float* xi0 = ximp + (size_t)(m_base + st_r) * 64 + (st_c << 3);

  float ssq_acc = 0.f, msum_acc = 0.f;

  // ---------- helpers ----------
  auto stage_wr = [&](int buf, const float4& v0, const float4& v1) {
    float* q = &In_s[buf][st_r][st_c << 3];
    q[0] = v0.x; q[1] = v0.y; q[2] = v0.z; q[3] = v0.w;
    q[4] = v1.x; q[5] = v1.y; q[6] = v1.z; q[7] = v1.w;
  };
  auto gates_chunk = [&](int buf, int ch, float acc[4]) {
    const float* inr = In_s[buf][mR];
    const float* wp0 = &W_s[wrow + 0][ch << 6];
    const float* wp1 = &W_s[wrow + 1][ch << 6];
    const float* wp2 = &W_s[wrow + 2][ch << 6];
    const float* wp3 = &W_s[wrow + 3][ch << 6];
#pragma unroll
    for (int k4 = 0; k4 < 16; ++k4) {
      float4 w0 = *(const float4*)(wp0 + (k4 << 2));
      float4 w1 = *(const float4*)(wp1 + (k4 << 2));
      float4 w2 = *(const float4*)(wp2 + (k4 << 2));
      float4 w3 = *(const float4*)(wp3 + (k4 << 2));
      float a0 = inr[(k4 << 2) + 0];
      float a1 = inr[(k4 << 2) + 1];
      float a2 = inr[(k4 << 2) + 2];
      float a3 = inr[(k4 << 2) + 3];
      acc[0] = fmaf(a0, w0.x, acc[0]); acc[0] = fmaf(a1, w0.y, acc[0]);
      acc[0] = fmaf(a2, w0.z, acc[0]); acc[0] = fmaf(a3, w0.w, acc[0]);
      acc[1] = fmaf(a0, w1.x, acc[1]); acc[1] = fmaf(a1, w1.y, acc[1]);
      acc[1] = fmaf(a2, w1.z, acc[1]); acc[1] = fmaf(a3, w1.w, acc[1]);
      acc[2] = fmaf(a0, w2.x, acc[2]); acc[2] = fmaf(a1, w2.y, acc[2]);
      acc[2] = fmaf(a2, w2.z, acc[2]); acc[2] = fmaf(a3, w2.w, acc[2]);
      acc[3] = fmaf(a0, w3.x, acc[3]); acc[3] = fmaf(a1, w3.y, acc[3]);
      acc[3] = fmaf(a2, w3.z, acc[3]); acc[3] = fmaf(a3, w3.w, acc[3]);
    }
  };
  auto xrec_chunk = [&](int buf, int ch, float& ax) {
    const float* inr = In_s[buf][mR];
    const float* wp = &Wo_s[nG][ch << 6];
#pragma unroll
    for (int k4 = 0; k4 < 16; ++k4) {
      float4 w = *(const float4*)(wp + (k4 << 2));
      ax = fmaf(inr[(k4 << 2) + 0], w.x, ax);
      ax = fmaf(inr[(k4 << 2) + 1], w.y, ax);
      ax = fmaf(inr[(k4 << 2) + 2], w.z, ax);
      ax = fmaf(inr[(k4 << 2) + 3], w.w, ax);
    }
  };
  auto do_update = [&](const float acc[4], float* hbo, float* cbo) {
    *(float4*)&GateS[(gate << 9) + (mR << 3) + hq] =
        make_float4(acc[0], acc[1], acc[2], acc[3]);
    __syncthreads();
    float iv = sigm_(GateS[(0 << 9) + (um << 3) + uh]);
    float fv = sigm_(GateS[(1 << 9) + (um << 3) + uh]);
    float gv = tanhf(GateS[(2 << 9) + (um << 3) + uh]);
    float ov = sigm_(GateS[(3 << 9) + (um << 3) + uh]);
    float cold = C_s[um][uh];
    float cn = fmaf(fv, cold, iv * gv);
    float hn = ov * tanhf(cn);
    C_s[um][uh] = cn;
    size_t off = (size_t)(m_base + um) * 256 + hbase + uh;
    hbo[off] = hn;
    cbo[off] = cn;
  };
  // wave-synchronous imputation producer: waves 0,1 -> rows b0, b0+1
  auto produce_ximp = [&](int tn) {
    if (tid < 128) {
      const int w = tid >> 6, l = tid & 63;
      const int row = b0 + w;
      float xv = X[((size_t)row * 256 + tn) * 64 + l];
      float mv = MM[((size_t)row * 256 + tn) * 64 + l];
      Xrow_s[w][l] = xv;
      float s = 0.f;
#pragma unroll 8
      for (int e = 0; e < 64; ++e) s = fmaf(Xrow_s[w][e], WimpT_s[e][l], s);
      ximp[(size_t)(tn & 1) * SZX + (size_t)row * 64 + l] =
          fmaf(xv, mv, s * (1.f - xv));
    }
  };

  // ---------- encoder phase setup ----------
  {
    int n = tid >> 4, c16 = tid & 15;
    const float* wsrc = ws + WENC + (size_t)(((n >> 3) << 8) + hbase + (n & 7)) * 576;
#pragma unroll
    for (int j = 0; j < 9; ++j) {
      int c4 = c16 * 9 + j;
      *(float4*)&W_s[n][c4 << 2] = *(const float4*)&wsrc[c4 << 2];
    }
    for (int i = tid; i < 4096; i += NTHR) {
      int d = i >> 6, e = i & 63;
      WimpT_s[e][d] = Wimp[i];
    }
    for (int i = tid; i < 576; i += NTHR) ((float*)C_s)[i] = 0.f;
  }
  float4 biav = *(const float4*)&ws[BENC + (gate << 8) + hbase + hq];
  __syncthreads();          // WimpT_s visible before produce
  produce_ximp(0);
  gbar(ws);

  // ---------- encoder scan ----------
  int p = 0;
  for (int t = 0; t < 256; ++t) {
    float4 pa[9], pb[9];
#pragma unroll
    for (int ch = 0; ch < 9; ++ch) {
      const float* bp;
      if (ch == 0)      bp = xi0 + (size_t)(t & 1) * SZX;
      else if (ch < 5)  bp = hb0 + (size_t)p * SZ + (size_t)((ch - 1) << 6);
      else              bp = cb0 + (size_t)p * SZ + (size_t)((ch - 5) << 6);
      pa[ch] = *(const float4*)bp;
      pb[ch] = *(const float4*)(bp + 4);
    }
    if (t < 255) produce_ximp(t + 1);
    float acc[4] = {biav.x, biav.y, biav.z, biav.w};
    stage_wr(0, pa[0], pb[0]);
#pragma unroll
    for (int ch = 0; ch < 9; ++ch) {
      __syncthreads();
      if (ch < 8) stage_wr((ch + 1) & 1, pa[ch + 1], pb[ch + 1]);
      gates_chunk(ch & 1, ch, acc);
    }
    do_update(acc, hbuf + (size_t)(p ^ 1) * SZ, cbuf + (size_t)(p ^ 1) * SZ);
    gbar(ws);
    p ^= 1;
  }
  // p == 0; c_T in cbuf[0]

  // ---------- AE heads + latent (own rows b0, b0+1) ----------
  {
    int rr = tid >> 8, j = tid & 255;
    Hrow_s[rr][j] = cbuf[(size_t)(b0 + rr) * 256 + j];
  }
  __syncthreads();
  {
    int rr = tid >> 8, u = tid & 255;
    float a = aeb[u];
    const float4* wr = (const float4*)(aeW + (size_t)u * 256);
#pragma unroll 4
    for (int j4 = 0; j4 < 64; ++j4) {
      float4 w = wr[j4];
      a = fmaf(Hrow_s[rr][(j4 << 2) + 0], w.x, a);
      a = fmaf(Hrow_s[rr][(j4 << 2) + 1], w.y, a);
      a = fmaf(Hrow_s[rr][(j4 << 2) + 2], w.z, a);
      a = fmaf(Hrow_s[rr][(j4 << 2) + 3], w.w, a);
    }
    cc_s[rr][u] = softplus_(a);
  }
  __syncthreads();
  if (tid < 128) {
    int rr = tid >> 6, sel = (tid >> 5) & 1, q = tid & 31;
    const float* Wm = sel ? stW : muW;
    float a = sel ? stb[q] : mub[q];
    const float4* wr = (const float4*)(Wm + (size_t)q * 256);
#pragma unroll 4
    for (int j4 = 0; j4 < 64; ++j4) {
      float4 w = wr[j4];
      a = fmaf(cc_s[rr][(j4 << 2) + 0], w.x, a);
      a = fmaf(cc_s[rr][(j4 << 2) + 1], w.y, a);
      a = fmaf(cc_s[rr][(j4 << 2) + 2], w.z, a);
      a = fmaf(cc_s[rr][(j4 << 2) + 3], w.w, a);
    }
    if (sel) std_s[rr][q] = a; else mu_s[rr][q] = a;
  }
  __syncthreads();
  if (tid < 64) {
    int rr = tid >> 5, q = tid & 31;
    float zv = fmaf(expf(0.5f * std_s[rr][q]), NZ[(size_t)(b0 + rr) * 32 + q], mu_s[rr][q]);
    z_s[rr][q] = zv;
    out[1 + (size_t)(b0 + rr) * 32 + q] = zv;
  }
  __syncthreads();
  {
    int rr = tid >> 8, u = tid & 255;
    float a = adb[u];
#pragma unroll
    for (int q = 0; q < 32; ++q) a = fmaf(z_s[rr][q], adW[(size_t)u * 32 + q], a);
    hbuf[(size_t)(b0 + rr) * 256 + u] = softplus_(a);
    cbuf[(size_t)(b0 + rr) * 256 + u] = 0.f;
  }
  if (tid < 128) {
    int wv = tid >> 6, ln = tid & 63;
    if (ln < 32) {
      float zd = z_s[wv][ln], mud = mu_s[wv][ln], sdd = std_s[wv][ln];
      float vt = expf(sdd);
      float l3p = -0.5f * (1.f + sdd);
      float lp[8], tk[8];
#pragma unroll
      for (int k = 0; k < 8; ++k) {
        float vc = softplus_(vcu[(k << 5) + ln]);
        float lvc = logf(vc + EPSF);
        float mc = mcu[(k << 5) + ln];
        float dz = zd - mc;
        float a_d = lvc + LOG2PIF + dz * dz / vc;
        float ive = 1.f / (vc + EPSF);
        float dm = mud - mc;
        float t_d = lvc + fmaf(vt, ive, dm * dm * ive);
#pragma unroll
        for (int off = 16; off > 0; off >>= 1) {
          a_d += __shfl_xor(a_d, off, 64);
          t_d += __shfl_xor(t_d, off, 64);
        }
        lp[k] = -0.5f * a_d;
        tk[k] = t_d;
      }
#pragma unroll
      for (int off = 16; off > 0; off >>= 1) l3p += __shfl_xor(l3p, off, 64);
      float phv[8], mx = -1e30f;
#pragma unroll
      for (int k = 0; k < 8; ++k) { phv[k] = pcu[k]; mx = fmaxf(mx, phv[k]); }
      float se = 0.f;
#pragma unroll
      for (int k = 0; k < 8; ++k) se += expf(phv[k] - mx);
      float lphi[8], lpf[8], mx2 = -1e30f;
#pragma unroll
      for (int k = 0; k < 8; ++k) {
        lphi[k] = logf(expf(phv[k] - mx) / se + EPSF);
        lpf[k] = lphi[k] + lp[k];
        mx2 = fmaxf(mx2, lpf[k]);
      }
      float s2 = 0.f;
#pragma unroll
      for (int k = 0; k < 8; ++k) s2 += expf(lpf[k] - mx2);
      float lse = mx2 + logf(s2);
      float l1 = 0.f, l2 = 0.f;
#pragma unroll
      for (int k = 0; k < 8; ++k) {
        float lg = lpf[k] - lse;
        float gm = expf(lg);
        l1 = fmaf(gm, tk[k], l1);
        l2 = fmaf(gm, lphi[k] - lg, l2);
      }
      if (ln == 0) {
        lat_s[wv][0] = 0.5f * l1;
        lat_s[wv][1] = -l2;
        lat_s[wv][2] = l3p;
      }
    }
  }
  __syncthreads();

  // ---------- decoder phase setup ----------
  {
    int n = tid >> 4, c16 = tid & 15;
    const float* wsrc = ws + WDEC + (size_t)(((n >> 3) << 8) + hbase + (n & 7)) * 512;
#pragma unroll
    for (int j = 0; j < 8; ++j) {
      int c4 = (c16 << 3) + j;
      *(float4*)&W_s[n][c4 << 2] = *(const float4*)&wsrc[c4 << 2];
    }
    if (mse_blk) {
      int r = tid >> 6, c4 = tid & 63;
      *(float4*)&Wo_s[r][c4 << 2] = *(const float4*)&oW[(size_t)((hi << 3) + r) * 256 + (c4 << 2)];
    }
    for (int i = tid; i < 576; i += NTHR) ((float*)C_s)[i] = 0.f;
  }
  biav = *(const float4*)&ws[BDEC + (gate << 8) + hbase + hq];
  float obv = mse_blk ? ob[(hi << 3) + nG] : 0.f;
  gbar(ws);

  // ---------- decoder scan (+ fused X_rec / masked MSE, one step behind) ----------
  for (int t = 0; t < 256; ++t) {
    const bool dm = mse_blk && (t >= 1);
    float4 pa[8], pb[8];
#pragma unroll
    for (int ch = 0; ch < 8; ++ch) {
      const float* bp = (ch < 4) ? hb0 + (size_t)p * SZ + (size_t)(ch << 6)
                                 : cb0 + (size_t)p * SZ + (size_t)((ch - 4) << 6);
      pa[ch] = *(const float4*)bp;
      pb[ch] = *(const float4*)(bp + 4);
    }
    if (dm) {
      if (tid < 128) {
        int r2 = tid >> 1, hf = tid & 1;
        *(float4*)&Xm_s[r2][hf << 2] =
            *(const float4*)&X[((size_t)(m_base + r2) * 256 + (t - 1)) * 64 + (hi << 3) + (hf << 2)];
      } else if (tid < 256) {
        int r2 = (tid - 128) >> 1, hf = tid & 1;
        *(float4*)&Mm_s[r2][hf << 2] =
            *(const float4*)&MM[((size_t)(m_base + r2) * 256 + (t - 1)) * 64 + (hi << 3) + (hf << 2)];
      }
    }
    float acc[4] = {biav.x, biav.y, biav.z, biav.w};
    float ax = 0.f;
    stage_wr(0, pa[0], pb[0]);
#pragma unroll
    for (int ch = 0; ch < 8; ++ch) {
      __syncthreads();
      if (ch < 7) stage_wr((ch + 1) & 1, pa[ch + 1], pb[ch + 1]);
      gates_chunk(ch & 1, ch, acc);
      if (dm && ch < 4) xrec_chunk(ch & 1, ch, ax);
    }
    if (dm) {
      float df = (ax + obv) - Xm_s[mR][nG];
      float mv = Mm_s[mR][nG];
      ssq_acc = fmaf(mv, df * df, ssq_acc);
      msum_acc += mv;
    }
    do_update(acc, hbuf + (size_t)(p ^ 1) * SZ, cbuf + (size_t)(p ^ 1) * SZ);
    gbar(ws);
    p ^= 1;
  }
  // tail: MSE for hs[255] (h-state in buffer p == 0)
  if (mse_blk) {
    float4 pa[4], pb[4];
#pragma unroll
    for (int ch = 0; ch < 4; ++ch) {
      const float* bp = hb0 + (size_t)p * SZ + (size_t)(ch << 6);
      pa[ch] = *(const float4*)bp;
      pb[ch] = *(const float4*)(bp + 4);
    }
    if (tid < 128) {
      int r2 = tid >> 1, hf = tid & 1;
      *(float4*)&Xm_s[r2][hf << 2] =
          *(const float4*)&X[((size_t)(m_base + r2) * 256 + 255) * 64 + (hi << 3) + (hf << 2)];
    } else if (tid < 256) {
      int r2 = (tid - 128) >> 1, hf = tid & 1;
      *(float4*)&Mm_s[r2][hf << 2] =
          *(const float4*)&MM[((size_t)(m_base + r2) * 256 + 255) * 64 + (hi << 3) + (hf << 2)];
    }
    float ax = 0.f;
    stage_wr(0, pa[0], pb[0]);
#pragma unroll
    for (int ch = 0; ch < 4; ++ch) {
      __syncthreads();
      if (ch < 3) stage_wr((ch + 1) & 1, pa[ch + 1], pb[ch + 1]);
      xrec_chunk(ch & 1, ch, ax);
    }
    float df = (ax + obv) - Xm_s[mR][nG];
    float mv = Mm_s[mR][nG];
    ssq_acc = fmaf(mv, df * df, ssq_acc);
    msum_acc += mv;
  }

  // ---------- per-block partials ----------
  __syncthreads();
  red_s[tid] = ssq_acc;
  __syncthreads();
  for (int s = 256; s > 0; s >>= 1) { if (tid < s) red_s[tid] += red_s[tid + s]; __syncthreads(); }
  if (tid == 0) part[(bid << 3) + 0] = red_s[0];
  __syncthreads();
  red_s[tid] = msum_acc;
  __syncthreads();
  for (int s = 256; s > 0; s >>= 1) { if (tid < s) red_s[tid] += red_s[tid + s]; __syncthreads(); }
  if (tid == 0) {
    part[(bid << 3) + 1] = red_s[0];
    part[(bid << 3) + 2] = lat_s[0][0] + lat_s[1][0];
    part[(bid << 3) + 3] = lat_s[0][1] + lat_s[1][1];
    part[(bid << 3) + 4] = lat_s[0][2] + lat_s[1][2];
  }
  gbar(ws);

  // ---------- final reduce + loss (block 0) ----------
  if (bid == 0) {
    for (int c = 0; c < 5; ++c) {
      red_s[tid] = (tid < 256) ? part[(tid << 3) + c] : 0.f;
      __syncthreads();
      for (int s = 256; s > 0; s >>= 1) { if (tid < s) red_s[tid] += red_s[tid + s]; __syncthreads(); }
      if (tid == 0) tot_s[c] = red_s[0];
      __syncthreads();
    }
    if (tid == 0) {
      float ssq = tot_s[0], msum = tot_s[1];
      float mse = ssq / (msum + 1e-12f);
      float recon = mse * 16384.f / msum;
      float latent = (tot_s[2] + tot_s[3] + tot_s[4]) / 512.f;
      out[0] = recon + latent;
    }
  }
}

extern "C" void kernel_launch(void* const* d_in, const int* in_sizes, int n_in,
                              void* d_out, int out_size, void* d_ws, size_t ws_size,
                              hipStream_t stream) {
  (void)in_sizes; (void)out_size;
  if (n_in < 29) return;
  if (ws_size < WS_NEED * sizeof(float)) return;
  const float* X    = (const float*)d_in[0];
  const float* MM   = (const float*)d_in[1];
  const float* NZ   = (const float*)d_in[2];
  const float* Wimp = (const float*)d_in[3];
  const float* eWih = (const float*)d_in[4];
  const float* ebih = (const float*)d_in[5];
  const float* eWhh = (const float*)d_in[6];
  const float* ebhh = (const float*)d_in[7];
  const float* eWch = (const float*)d_in[8];
  const float* ebch = (const float*)d_in[9];
  const float* dbih = (const float*)d_in[11];
  const float* dWhh = (const float*)d_in[12];
  const float* dbhh = (const float*)d_in[13];
  const float* dWch = (const float*)d_in[14];
  const float* dbch = (const float*)d_in[15];
  const float* aeW  = (const float*)d_in[16];
  const float* aeb  = (const float*)d_in[17];
  const float* adW  = (const float*)d_in[18];
  const float* adb  = (const float*)d_in[19];
  const float* muW  = (const float*)d_in[20];
  const float* mub  = (const float*)d_in[21];
  const float* stW  = (const float*)d_in[22];
  const float* stb  = (const float*)d_in[23];
  const float* oW   = (const float*)d_in[24];
  const float* ob   = (const float*)d_in[25];
  const float* mcu  = (const float*)d_in[26];
  const float* vcu  = (const float*)d_in[27];
  const float* pcu  = (const float*)d_in[28];
  float* ws = (float*)d_ws;

  vader_init<<<512, 256, 0, stream>>>(eWih, ebih, eWhh, ebhh, eWch, ebch,
                                      dbih, dWhh, dbhh, dWch, dbch, ws);
  vader_main<<<NBLK, NTHR, 0, stream>>>(X, MM, NZ, Wimp, aeW, aeb, adW, adb,
                                        muW, mub, stW, stb, oW, ob, mcu, vcu, pcu,
                                        ws, (float*)d_out);
}

// Round 9
// 153609.766 us; speedup vs baseline: 1.0335x; 1.0335x over previous
//
#include <hip/hip_runtime.h>
#include <math.h>

#define NBLK 256
#define NTHR 512

constexpr float EPSF = 1e-9f;
constexpr float LOG2PIF = 1.8378770664093453f;

// ---- workspace layout (float offsets) ----
constexpr size_t OFF_CNT  = 0;
constexpr size_t OFF_GEN  = 32;
constexpr size_t OFF_PART = 128;
constexpr size_t WENC = 4096;                        // [1024][576]
constexpr size_t BENC = WENC + (size_t)1024 * 576;   // [1024]
constexpr size_t WDEC = BENC + 1024;                 // [1024][512]
constexpr size_t BDEC = WDEC + (size_t)1024 * 512;   // [1024]
constexpr size_t HBUF = BDEC + 1024;                 // [2][512][256]
constexpr size_t CBUF = HBUF + (size_t)2 * 512 * 256;
constexpr size_t XIMP = CBUF + (size_t)2 * 512 * 256; // [2][512][64]
constexpr size_t WS_NEED = XIMP + (size_t)2 * 512 * 64;

constexpr size_t SZ  = (size_t)512 * 256;
constexpr size_t SZX = (size_t)512 * 64;

__device__ __forceinline__ float sigm_(float x) { return 1.f / (1.f + expf(-x)); }
__device__ __forceinline__ float softplus_(float x) { return x > 20.f ? x : log1pf(expf(x)); }

// PROVEN grid barrier (r1/r2/r7/r8 PASS) — verbatim, do not touch.
__device__ __forceinline__ void gbar(float* ws) {
  __syncthreads();
  if (threadIdx.x == 0) {
    __threadfence();
    unsigned* cnt = (unsigned*)(ws + OFF_CNT);
    unsigned* gen = (unsigned*)(ws + OFF_GEN);
    unsigned g = __hip_atomic_load(gen, __ATOMIC_RELAXED, __HIP_MEMORY_SCOPE_AGENT);
    unsigned a = __hip_atomic_fetch_add(cnt, 1u, __ATOMIC_ACQ_REL, __HIP_MEMORY_SCOPE_AGENT);
    if (a == NBLK - 1) {
      __hip_atomic_store(cnt, 0u, __ATOMIC_RELAXED, __HIP_MEMORY_SCOPE_AGENT);
      __hip_atomic_store(gen, g + 1u, __ATOMIC_RELEASE, __HIP_MEMORY_SCOPE_AGENT);
    } else {
      while (__hip_atomic_load(gen, __ATOMIC_RELAXED, __HIP_MEMORY_SCOPE_AGENT) == g) {
        __builtin_amdgcn_s_sleep(2);
      }
    }
    __threadfence();
  }
  __syncthreads();
}

__global__ void vader_init(
    const float* __restrict__ eWih, const float* __restrict__ ebih,
    const float* __restrict__ eWhh, const float* __restrict__ ebhh,
    const float* __restrict__ eWch, const float* __restrict__ ebch,
    const float* __restrict__ dbih, const float* __restrict__ dWhh,
    const float* __restrict__ dbhh, const float* __restrict__ dWch,
    const float* __restrict__ dbch, float* __restrict__ ws) {
  const int i0 = blockIdx.x * blockDim.x + threadIdx.x;
  const int stride = gridDim.x * blockDim.x;
  for (int i = i0; i < 4096; i += stride) ws[i] = 0.f;
  for (int i = i0; i < 512 * 256; i += stride) {
    ws[HBUF + i] = 0.f;
    ws[CBUF + i] = 0.f;
  }
  for (int i = i0; i < 1024 * 576; i += stride) {
    int n = i / 576, k = i - n * 576;
    float v;
    if (k < 64)       v = eWih[n * 64 + k];
    else if (k < 320) v = eWhh[n * 256 + (k - 64)];
    else {
      int j = k - 320;
      if (n < 512)      v = eWch[n * 256 + j];
      else if (n < 768) v = 0.f;
      else              v = eWch[(n - 256) * 256 + j];
    }
    ws[WENC + i] = v;
  }
  for (int i = i0; i < 1024 * 512; i += stride) {
    int n = i >> 9, k = i & 511;
    float v;
    if (k < 256) v = dWhh[n * 256 + k];
    else {
      int j = k - 256;
      if (n < 512)      v = dWch[n * 256 + j];
      else if (n < 768) v = 0.f;
      else              v = dWch[(n - 256) * 256 + j];
    }
    ws[WDEC + i] = v;
  }
  for (int i = i0; i < 1024; i += stride) {
    float bce = (i < 512) ? ebch[i] : ((i < 768) ? 0.f : ebch[i - 256]);
    ws[BENC + i] = ebih[i] + ebhh[i] + bce;
    float bcd = (i < 512) ? dbch[i] : ((i < 768) ? 0.f : dbch[i - 256]);
    ws[BDEC + i] = dbih[i] + dbhh[i] + bcd;
  }
}

// NOTE: never hold a wide load batch across __syncthreads in this kernel —
// 18-float4 batches spilled to scratch and the per-step threadfence turned
// that into ~487 GB of HBM traffic (r4/r7/r8). Interleave loads, <=2 live.
__global__ __launch_bounds__(NTHR, 1) void vader_main(
    const float* __restrict__ X, const float* __restrict__ MM, const float* __restrict__ NZ,
    const float* __restrict__ Wimp,
    const float* __restrict__ aeW, const float* __restrict__ aeb,
    const float* __restrict__ adW, const float* __restrict__ adb,
    const float* __restrict__ muW, const float* __restrict__ mub,
    const float* __restrict__ stW, const float* __restrict__ stb,
    const float* __restrict__ oW, const float* __restrict__ ob,
    const float* __restrict__ mcu, const float* __restrict__ vcu, const float* __restrict__ pcu,
    float* __restrict__ ws, float* __restrict__ out) {
  const int bid = blockIdx.x, tid = threadIdx.x;
  const int mi = bid & 7, hi = bid >> 3;
  const int m_base = mi << 6;
  const int hbase = hi << 3;
  const int b0 = bid << 1;

  // ---- LDS ----
  __shared__ float In_s[2][64][65];              // odd stride: b32 reads 2-way = free
  __shared__ __align__(16) float W_s[32][576];   // 73.7 KB resident gate-weight slice
  __shared__ __align__(16) char u1_raw[17408];   // enc: WimpT | dec: Wo_s + Xm/Mm
  __shared__ __align__(16) char u2_raw[8192];    // GateS | heads arrays | red_s
  __shared__ float C_s[64][9];
  __shared__ float Xrow_s[2][64];
  __shared__ float lat_s[2][3];
  __shared__ float tot_s[5];

  float (*WimpT_s)[68] = (float(*)[68])u1_raw;                 // [64][68]
  float (*Wo_s)[260]   = (float(*)[260])u1_raw;                // [8][260]
  float (*Xm_s)[12]    = (float(*)[12])(u1_raw + 8320);        // [64][12]
  float (*Mm_s)[12]    = (float(*)[12])(u1_raw + 8320 + 3072); // [64][12]
  float* GateS         = (float*)u2_raw;                        // [4][64][8]
  float (*Hrow_s)[256] = (float(*)[256])u2_raw;
  float (*cc_s)[256]   = (float(*)[256])(u2_raw + 2048);
  float (*mu_s)[32]    = (float(*)[32])(u2_raw + 4096);
  float (*std_s)[32]   = (float(*)[32])(u2_raw + 4352);
  float (*z_s)[32]     = (float(*)[32])(u2_raw + 4608);
  float* red_s         = (float*)u2_raw;                        // [512] final only

  float* hbuf = ws + HBUF;
  float* cbuf = ws + CBUF;
  float* ximp = ws + XIMP;
  float* part = ws + OFF_PART;

  // gates mapping: thread = (row mR, col-group nG of 4 gate-cols)
  const int mR = tid & 63, nG = tid >> 6;
  const int gate = nG >> 1, hq = (nG & 1) << 2;
  const int wrow = (gate << 3) + hq;
  const int st_r = tid >> 3, st_c = tid & 7;     // staging: row st_r, 8 floats @ col st_c*8
  const int um = tid >> 3, uh = tid & 7;
  const bool mse_blk = (hi < 8);

  const float* hb0 = hbuf + (size_t)(m_base + st_r) * 256 + (st_c << 3);
  const float* cb0 = cbuf + (size_t)(m_base + st_r) * 256 + (st_c << 3);
  const float* xi0 = ximp + (size_t)(m_base + st_r) * 64 + (st_c << 3);

  float ssq_acc = 0.f, msum_acc = 0.f;

  // ---------- helpers ----------
  auto stage_wr = [&](int buf, const float4& v0, const float4& v1) {
    float* q = &In_s[buf][st_r][st_c << 3];
    q[0] = v0.x; q[1] = v0.y; q[2] = v0.z; q[3] = v0.w;
    q[4] = v1.x; q[5] = v1.y; q[6] = v1.z; q[7] = v1.w;
  };
  auto gates_chunk = [&](int buf, int ch, float acc[4]) {
    const float* inr = In_s[buf][mR];
    const float* wp0 = &W_s[wrow + 0][ch << 6];
    const float* wp1 = &W_s[wrow + 1][ch << 6];
    const float* wp2 = &W_s[wrow + 2][ch << 6];
    const float* wp3 = &W_s[wrow + 3][ch << 6];
#pragma unroll
    for (int k4 = 0; k4 < 16; ++k4) {
      float4 w0 = *(const float4*)(wp0 + (k4 << 2));
      float4 w1 = *(const float4*)(wp1 + (k4 << 2));
      float4 w2 = *(const float4*)(wp2 + (k4 << 2));
      float4 w3 = *(const float4*)(wp3 + (k4 << 2));
      float a0 = inr[(k4 << 2) + 0];
      float a1 = inr[(k4 << 2) + 1];
      float a2 = inr[(k4 << 2) + 2];
      float a3 = inr[(k4 << 2) + 3];
      acc[0] = fmaf(a0, w0.x, acc[0]); acc[0] = fmaf(a1, w0.y, acc[0]);
      acc[0] = fmaf(a2, w0.z, acc[0]); acc[0] = fmaf(a3, w0.w, acc[0]);
      acc[1] = fmaf(a0, w1.x, acc[1]); acc[1] = fmaf(a1, w1.y, acc[1]);
      acc[1] = fmaf(a2, w1.z, acc[1]); acc[1] = fmaf(a3, w1.w, acc[1]);
      acc[2] = fmaf(a0, w2.x, acc[2]); acc[2] = fmaf(a1, w2.y, acc[2]);
      acc[2] = fmaf(a2, w2.z, acc[2]); acc[2] = fmaf(a3, w2.w, acc[2]);
      acc[3] = fmaf(a0, w3.x, acc[3]); acc[3] = fmaf(a1, w3.y, acc[3]);
      acc[3] = fmaf(a2, w3.z, acc[3]); acc[3] = fmaf(a3, w3.w, acc[3]);
    }
  };
  auto xrec_chunk = [&](int buf, int ch, float& ax) {
    const float* inr = In_s[buf][mR];
    const float* wp = &Wo_s[nG][ch << 6];
#pragma unroll
    for (int k4 = 0; k4 < 16; ++k4) {
      float4 w = *(const float4*)(wp + (k4 << 2));
      ax = fmaf(inr[(k4 << 2) + 0], w.x, ax);
      ax = fmaf(inr[(k4 << 2) + 1], w.y, ax);
      ax = fmaf(inr[(k4 << 2) + 2], w.z, ax);
      ax = fmaf(inr[(k4 << 2) + 3], w.w, ax);
    }
  };
  auto do_update = [&](const float acc[4], float* hbo, float* cbo) {
    *(float4*)&GateS[(gate << 9) + (mR << 3) + hq] =
        make_float4(acc[0], acc[1], acc[2], acc[3]);
    __syncthreads();
    float iv = sigm_(GateS[(0 << 9) + (um << 3) + uh]);
    float fv = sigm_(GateS[(1 << 9) + (um << 3) + uh]);
    float gv = tanhf(GateS[(2 << 9) + (um << 3) + uh]);
    float ov = sigm_(GateS[(3 << 9) + (um << 3) + uh]);
    float cold = C_s[um][uh];
    float cn = fmaf(fv, cold, iv * gv);
    float hn = ov * tanhf(cn);
    C_s[um][uh] = cn;
    size_t off = (size_t)(m_base + um) * 256 + hbase + uh;
    hbo[off] = hn;
    cbo[off] = cn;
  };
  // wave-synchronous imputation producer: waves 0,1 -> rows b0, b0+1
  auto produce_ximp = [&](int tn) {
    if (tid < 128) {
      const int w = tid >> 6, l = tid & 63;
      const int row = b0 + w;
      float xv = X[((size_t)row * 256 + tn) * 64 + l];
      float mv = MM[((size_t)row * 256 + tn) * 64 + l];
      Xrow_s[w][l] = xv;
      float s = 0.f;
#pragma unroll 8
      for (int e = 0; e < 64; ++e) s = fmaf(Xrow_s[w][e], WimpT_s[e][l], s);
      ximp[(size_t)(tn & 1) * SZX + (size_t)row * 64 + l] =
          fmaf(xv, mv, s * (1.f - xv));
    }
  };

  // ---------- encoder phase setup ----------
  {
    int n = tid >> 4, c16 = tid & 15;
    const float* wsrc = ws + WENC + (size_t)(((n >> 3) << 8) + hbase + (n & 7)) * 576;
#pragma unroll
    for (int j = 0; j < 9; ++j) {
      int c4 = c16 * 9 + j;
      *(float4*)&W_s[n][c4 << 2] = *(const float4*)&wsrc[c4 << 2];
    }
    for (int i = tid; i < 4096; i += NTHR) {
      int d = i >> 6, e = i & 63;
      WimpT_s[e][d] = Wimp[i];
    }
    for (int i = tid; i < 576; i += NTHR) ((float*)C_s)[i] = 0.f;
  }
  float4 biav = *(const float4*)&ws[BENC + (gate << 8) + hbase + hq];
  __syncthreads();          // WimpT_s visible before produce
  produce_ximp(0);
  gbar(ws);

  // ---------- encoder scan (r2-style interleaved staging: <=2 float4 pairs live) ----------
  int p = 0;
  for (int t = 0; t < 256; ++t) {
    float4 r0, r1;
    {
      const float* bp = xi0 + (size_t)(t & 1) * SZX;
      r0 = *(const float4*)bp;
      r1 = *(const float4*)(bp + 4);
    }
    if (t < 255) produce_ximp(t + 1);
    float acc[4] = {biav.x, biav.y, biav.z, biav.w};
    stage_wr(0, r0, r1);
    __syncthreads();
#pragma unroll
    for (int ch = 0; ch < 9; ++ch) {
      if (ch < 8) {
        const float* np = (ch < 4) ? hb0 + (size_t)p * SZ + (size_t)(ch << 6)
                                   : cb0 + (size_t)p * SZ + (size_t)((ch - 4) << 6);
        r0 = *(const float4*)np;
        r1 = *(const float4*)(np + 4);
      }
      gates_chunk(ch & 1, ch, acc);          // compute hides load latency
      if (ch < 8) stage_wr((ch + 1) & 1, r0, r1);
      __syncthreads();
    }
    do_update(acc, hbuf + (size_t)(p ^ 1) * SZ, cbuf + (size_t)(p ^ 1) * SZ);
    gbar(ws);
    p ^= 1;
  }
  // p == 0; c_T in cbuf[0]

  // ---------- AE heads + latent (own rows b0, b0+1) ----------
  {
    int rr = tid >> 8, j = tid & 255;
    Hrow_s[rr][j] = cbuf[(size_t)(b0 + rr) * 256 + j];
  }
  __syncthreads();
  {
    int rr = tid >> 8, u = tid & 255;
    float a = aeb[u];
    const float4* wr = (const float4*)(aeW + (size_t)u * 256);
#pragma unroll 4
    for (int j4 = 0; j4 < 64; ++j4) {
      float4 w = wr[j4];
      a = fmaf(Hrow_s[rr][(j4 << 2) + 0], w.x, a);
      a = fmaf(Hrow_s[rr][(j4 << 2) + 1], w.y, a);
      a = fmaf(Hrow_s[rr][(j4 << 2) + 2], w.z, a);
      a = fmaf(Hrow_s[rr][(j4 << 2) + 3], w.w, a);
    }
    cc_s[rr][u] = softplus_(a);
  }
  __syncthreads();
  if (tid < 128) {
    int rr = tid >> 6, sel = (tid >> 5) & 1, q = tid & 31;
    const float* Wm = sel ? stW : muW;
    float a = sel ? stb[q] : mub[q];
    const float4* wr = (const float4*)(Wm + (size_t)q * 256);
#pragma unroll 4
    for (int j4 = 0; j4 < 64; ++j4) {
      float4 w = wr[j4];
      a = fmaf(cc_s[rr][(j4 << 2) + 0], w.x, a);
      a = fmaf(cc_s[rr][(j4 << 2) + 1], w.y, a);
      a = fmaf(cc_s[rr][(j4 << 2) + 2], w.z, a);
      a = fmaf(cc_s[rr][(j4 << 2) + 3], w.w, a);
    }
    if (sel) std_s[rr][q] = a; else mu_s[rr][q] = a;
  }
  __syncthreads();
  if (tid < 64) {
    int rr = tid >> 5, q = tid & 31;
    float zv = fmaf(expf(0.5f * std_s[rr][q]), NZ[(size_t)(b0 + rr) * 32 + q], mu_s[rr][q]);
    z_s[rr][q] = zv;
    out[1 + (size_t)(b0 + rr) * 32 + q] = zv;
  }
  __syncthreads();
  {
    int rr = tid >> 8, u = tid & 255;
    float a = adb[u];
#pragma unroll
    for (int q = 0; q < 32; ++q) a = fmaf(z_s[rr][q], adW[(size_t)u * 32 + q], a);
    hbuf[(size_t)(b0 + rr) * 256 + u] = softplus_(a);
    cbuf[(size_t)(b0 + rr) * 256 + u] = 0.f;
  }
  if (tid < 128) {
    int wv = tid >> 6, ln = tid & 63;
    if (ln < 32) {
      float zd = z_s[wv][ln], mud = mu_s[wv][ln], sdd = std_s[wv][ln];
      float vt = expf(sdd);
      float l3p = -0.5f * (1.f + sdd);
      float lp[8], tk[8];
#pragma unroll
      for (int k = 0; k < 8; ++k) {
        float vc = softplus_(vcu[(k << 5) + ln]);
        float lvc = logf(vc + EPSF);
        float mc = mcu[(k << 5) + ln];
        float dz = zd - mc;
        float a_d = lvc + LOG2PIF + dz * dz / vc;
        float ive = 1.f / (vc + EPSF);
        float dm = mud - mc;
        float t_d = lvc + fmaf(vt, ive, dm * dm * ive);
#pragma unroll
        for (int off = 16; off > 0; off >>= 1) {
          a_d += __shfl_xor(a_d, off, 64);
          t_d += __shfl_xor(t_d, off, 64);
        }
        lp[k] = -0.5f * a_d;
        tk[k] = t_d;
      }
#pragma unroll
      for (int off = 16; off > 0; off >>= 1) l3p += __shfl_xor(l3p, off, 64);
      float phv[8], mx = -1e30f;
#pragma unroll
      for (int k = 0; k < 8; ++k) { phv[k] = pcu[k]; mx = fmaxf(mx, phv[k]); }
      float se = 0.f;
#pragma unroll
      for (int k = 0; k < 8; ++k) se += expf(phv[k] - mx);
      float lphi[8], lpf[8], mx2 = -1e30f;
#pragma unroll
      for (int k = 0; k < 8; ++k) {
        lphi[k] = logf(expf(phv[k] - mx) / se + EPSF);
        lpf[k] = lphi[k] + lp[k];
        mx2 = fmaxf(mx2, lpf[k]);
      }
      float s2 = 0.f;
#pragma unroll
      for (int k = 0; k < 8; ++k) s2 += expf(lpf[k] - mx2);
      float lse = mx2 + logf(s2);
      float l1 = 0.f, l2 = 0.f;
#pragma unroll
      for (int k = 0; k < 8; ++k) {
        float lg = lpf[k] - lse;
        float gm = expf(lg);
        l1 = fmaf(gm, tk[k], l1);
        l2 = fmaf(gm, lphi[k] - lg, l2);
      }
      if (ln == 0) {
        lat_s[wv][0] = 0.5f * l1;
        lat_s[wv][1] = -l2;
        lat_s[wv][2] = l3p;
      }
    }
  }
  __syncthreads();

  // ---------- decoder phase setup ----------
  {
    int n = tid >> 4, c16 = tid & 15;
    const float* wsrc = ws + WDEC + (size_t)(((n >> 3) << 8) + hbase + (n & 7)) * 512;
#pragma unroll
    for (int j = 0; j < 8; ++j) {
      int c4 = (c16 << 3) + j;
      *(float4*)&W_s[n][c4 << 2] = *(const float4*)&wsrc[c4 << 2];
    }
    if (mse_blk) {
      int r = tid >> 6, c4 = tid & 63;
      *(float4*)&Wo_s[r][c4 << 2] = *(const float4*)&oW[(size_t)((hi << 3) + r) * 256 + (c4 << 2)];
    }
    for (int i = tid; i < 576; i += NTHR) ((float*)C_s)[i] = 0.f;
  }
  biav = *(const float4*)&ws[BDEC + (gate << 8) + hbase + hq];
  float obv = mse_blk ? ob[(hi << 3) + nG] : 0.f;
  gbar(ws);

  // ---------- decoder scan (+ fused X_rec / masked MSE, one step behind) ----------
  for (int t = 0; t < 256; ++t) {
    const bool dm = mse_blk && (t >= 1);
    float4 r0, r1;
    {
      const float* bp = hb0 + (size_t)p * SZ;
      r0 = *(const float4*)bp;
      r1 = *(const float4*)(bp + 4);
    }
    if (dm) {
      if (tid < 128) {
        int r2 = tid >> 1, hf = tid & 1;
        *(float4*)&Xm_s[r2][hf << 2] =
            *(const float4*)&X[((size_t)(m_base + r2) * 256 + (t - 1)) * 64 + (hi << 3) + (hf << 2)];
      } else if (tid < 256) {
        int r2 = (tid - 128) >> 1, hf = tid & 1;
        *(float4*)&Mm_s[r2][hf << 2] =
            *(const float4*)&MM[((size_t)(m_base + r2) * 256 + (t - 1)) * 64 + (hi << 3) + (hf << 2)];
      }
    }
    float acc[4] = {biav.x, biav.y, biav.z, biav.w};
    float ax = 0.f;
    stage_wr(0, r0, r1);
    __syncthreads();
#pragma unroll
    for (int ch = 0; ch < 8; ++ch) {
      if (ch < 7) {
        const float* np = (ch < 3) ? hb0 + (size_t)p * SZ + (size_t)((ch + 1) << 6)
                                   : cb0 + (size_t)p * SZ + (size_t)((ch - 3) << 6);
        r0 = *(const float4*)np;
        r1 = *(const float4*)(np + 4);
      }
      gates_chunk(ch & 1, ch, acc);
      if (dm && ch < 4) xrec_chunk(ch & 1, ch, ax);
      if (ch < 7) stage_wr((ch + 1) & 1, r0, r1);
      __syncthreads();
    }
    if (dm) {
      float df = (ax + obv) - Xm_s[mR][nG];
      float mv = Mm_s[mR][nG];
      ssq_acc = fmaf(mv, df * df, ssq_acc);
      msum_acc += mv;
    }
    do_update(acc, hbuf + (size_t)(p ^ 1) * SZ, cbuf + (size_t)(p ^ 1) * SZ);
    gbar(ws);
    p ^= 1;
  }
  // tail: MSE for hs[255] (h-state in buffer p == 0)
  if (mse_blk) {
    float4 r0, r1;
    {
      const float* bp = hb0 + (size_t)p * SZ;
      r0 = *(const float4*)bp;
      r1 = *(const float4*)(bp + 4);
    }
    if (tid < 128) {
      int r2 = tid >> 1, hf = tid & 1;
      *(float4*)&Xm_s[r2][hf << 2] =
          *(const float4*)&X[((size_t)(m_base + r2) * 256 + 255) * 64 + (hi << 3) + (hf << 2)];
    } else if (tid < 256) {
      int r2 = (tid - 128) >> 1, hf = tid & 1;
      *(float4*)&Mm_s[r2][hf << 2] =
          *(const float4*)&MM[((size_t)(m_base + r2) * 256 + 255) * 64 + (hi << 3) + (hf << 2)];
    }
    float ax = 0.f;
    stage_wr(0, r0, r1);
    __syncthreads();
#pragma unroll
    for (int ch = 0; ch < 4; ++ch) {
      if (ch < 3) {
        const float* np = hb0 + (size_t)p * SZ + (size_t)((ch + 1) << 6);
        r0 = *(const float4*)np;
        r1 = *(const float4*)(np + 4);
      }
      xrec_chunk(ch & 1, ch, ax);
      if (ch < 3) stage_wr((ch + 1) & 1, r0, r1);
      __syncthreads();
    }
    float df = (ax + obv) - Xm_s[mR][nG];
    float mv = Mm_s[mR][nG];
    ssq_acc = fmaf(mv, df * df, ssq_acc);
    msum_acc += mv;
  }

  // ---------- per-block partials ----------
  __syncthreads();
  red_s[tid] = ssq_acc;
  __syncthreads();
  for (int s = 256; s > 0; s >>= 1) { if (tid < s) red_s[tid] += red_s[tid + s]; __syncthreads(); }
  if (tid == 0) part[(bid << 3) + 0] = red_s[0];
  __syncthreads();
  red_s[tid] = msum_acc;
  __syncthreads();
  for (int s = 256; s > 0; s >>= 1) { if (tid < s) red_s[tid] += red_s[tid + s]; __syncthreads(); }
  if (tid == 0) {
    part[(bid << 3) + 1] = red_s[0];
    part[(bid << 3) + 2] = lat_s[0][0] + lat_s[1][0];
    part[(bid << 3) + 3] = lat_s[0][1] + lat_s[1][1];
    part[(bid << 3) + 4] = lat_s[0][2] + lat_s[1][2];
  }
  gbar(ws);

  // ---------- final reduce + loss (block 0) ----------
  if (bid == 0) {
    for (int c = 0; c < 5; ++c) {
      red_s[tid] = (tid < 256) ? part[(tid << 3) + c] : 0.f;
      __syncthreads();
      for (int s = 256; s > 0; s >>= 1) { if (tid < s) red_s[tid] += red_s[tid + s]; __syncthreads(); }
      if (tid == 0) tot_s[c] = red_s[0];
      __syncthreads();
    }
    if (tid == 0) {
      float ssq = tot_s[0], msum = tot_s[1];
      float mse = ssq / (msum + 1e-12f);
      float recon = mse * 16384.f / msum;
      float latent = (tot_s[2] + tot_s[3] + tot_s[4]) / 512.f;
      out[0] = recon + latent;
    }
  }
}

extern "C" void kernel_launch(void* const* d_in, const int* in_sizes, int n_in,
                              void* d_out, int out_size, void* d_ws, size_t ws_size,
                              hipStream_t stream) {
  (void)in_sizes; (void)out_size;
  if (n_in < 29) return;
  if (ws_size < WS_NEED * sizeof(float)) return;
  const float* X    = (const float*)d_in[0];
  const float* MM   = (const float*)d_in[1];
  const float* NZ   = (const float*)d_in[2];
  const float* Wimp = (const float*)d_in[3];
  const float* eWih = (const float*)d_in[4];
  const float* ebih = (const float*)d_in[5];
  const float* eWhh = (const float*)d_in[6];
  const float* ebhh = (const float*)d_in[7];
  const float* eWch = (const float*)d_in[8];
  const float* ebch = (const float*)d_in[9];
  const float* dbih = (const float*)d_in[11];
  const float* dWhh = (const float*)d_in[12];
  const float* dbhh = (const float*)d_in[13];
  const float* dWch = (const float*)d_in[14];
  const float* dbch = (const float*)d_in[15];
  const float* aeW  = (const float*)d_in[16];
  const float* aeb  = (const float*)d_in[17];
  const float* adW  = (const float*)d_in[18];
  const float* adb  = (const float*)d_in[19];
  const float* muW  = (const float*)d_in[20];
  const float* mub  = (const float*)d_in[21];
  const float* stW  = (const float*)d_in[22];
  const float* stb  = (const float*)d_in[23];
  const float* oW   = (const float*)d_in[24];
  const float* ob   = (const float*)d_in[25];
  const float* mcu  = (const float*)d_in[26];
  const float* vcu  = (const float*)d_in[27];
  const float* pcu  = (const float*)d_in[28];
  float* ws = (float*)d_ws;

  vader_init<<<512, 256, 0, stream>>>(eWih, ebih, eWhh, ebhh, eWch, ebch,
                                      dbih, dWhh, dbhh, dWch, dbch, ws);
  vader_main<<<NBLK, NTHR, 0, stream>>>(X, MM, NZ, Wimp, aeW, aeb, adW, adb,
                                        muW, mub, stW, stb, oW, ob, mcu, vcu, pcu,
                                        ws, (float*)d_out);
}

// Round 10
// 18267.999 us; speedup vs baseline: 8.6900x; 8.4087x over previous
//
#include <hip/hip_runtime.h>
#include <math.h>

#define NBLK 256
#define NTHR 512

constexpr float EPSF = 1e-9f;
constexpr float LOG2PIF = 1.8378770664093453f;

// ---- workspace layout (float offsets) ----
constexpr size_t OFF_CNT  = 0;
constexpr size_t OFF_GEN  = 32;
constexpr size_t OFF_PART = 128;
constexpr size_t WENC = 4096;                        // [1024][576]
constexpr size_t BENC = WENC + (size_t)1024 * 576;   // [1024]
constexpr size_t WDEC = BENC + 1024;                 // [1024][512]
constexpr size_t BDEC = WDEC + (size_t)1024 * 512;   // [1024]
constexpr size_t HBUF = BDEC + 1024;                 // [2][512][256]
constexpr size_t CBUF = HBUF + (size_t)2 * 512 * 256;
constexpr size_t XIMP = CBUF + (size_t)2 * 512 * 256; // [2][512][64]
constexpr size_t WS_NEED = XIMP + (size_t)2 * 512 * 64;

constexpr size_t SZ = (size_t)512 * 256;

__device__ __forceinline__ float sigm_(float x) { return 1.f / (1.f + expf(-x)); }
__device__ __forceinline__ float softplus_(float x) { return x > 20.f ? x : log1pf(expf(x)); }

__device__ __forceinline__ void gbar(float* ws) {
  __syncthreads();
  if (threadIdx.x == 0) {
    __threadfence();
    unsigned* cnt = (unsigned*)(ws + OFF_CNT);
    unsigned* gen = (unsigned*)(ws + OFF_GEN);
    unsigned g = __hip_atomic_load(gen, __ATOMIC_RELAXED, __HIP_MEMORY_SCOPE_AGENT);
    unsigned a = __hip_atomic_fetch_add(cnt, 1u, __ATOMIC_ACQ_REL, __HIP_MEMORY_SCOPE_AGENT);
    if (a == NBLK - 1) {
      __hip_atomic_store(cnt, 0u, __ATOMIC_RELAXED, __HIP_MEMORY_SCOPE_AGENT);
      __hip_atomic_store(gen, g + 1u, __ATOMIC_RELEASE, __HIP_MEMORY_SCOPE_AGENT);
    } else {
      while (__hip_atomic_load(gen, __ATOMIC_RELAXED, __HIP_MEMORY_SCOPE_AGENT) == g) {
        __builtin_amdgcn_s_sleep(2);
      }
    }
    __threadfence();
  }
  __syncthreads();
}

__global__ void vader_init(
    const float* __restrict__ eWih, const float* __restrict__ ebih,
    const float* __restrict__ eWhh, const float* __restrict__ ebhh,
    const float* __restrict__ eWch, const float* __restrict__ ebch,
    const float* __restrict__ dbih, const float* __restrict__ dWhh,
    const float* __restrict__ dbhh, const float* __restrict__ dWch,
    const float* __restrict__ dbch, float* __restrict__ ws) {
  const int i0 = blockIdx.x * blockDim.x + threadIdx.x;
  const int stride = gridDim.x * blockDim.x;
  for (int i = i0; i < 4096; i += stride) ws[i] = 0.f;
  for (int i = i0; i < 512 * 256; i += stride) {
    ws[HBUF + i] = 0.f;
    ws[CBUF + i] = 0.f;
  }
  for (int i = i0; i < 1024 * 576; i += stride) {
    int n = i / 576, k = i - n * 576;
    float v;
    if (k < 64)       v = eWih[n * 64 + k];
    else if (k < 320) v = eWhh[n * 256 + (k - 64)];
    else {
      int j = k - 320;
      if (n < 512)      v = eWch[n * 256 + j];
      else if (n < 768) v = 0.f;
      else              v = eWch[(n - 256) * 256 + j];
    }
    ws[WENC + i] = v;
  }
  for (int i = i0; i < 1024 * 512; i += stride) {
    int n = i >> 9, k = i & 511;
    float v;
    if (k < 256) v = dWhh[n * 256 + k];
    else {
      int j = k - 256;
      if (n < 512)      v = dWch[n * 256 + j];
      else if (n < 768) v = 0.f;
      else              v = dWch[(n - 256) * 256 + j];
    }
    ws[WDEC + i] = v;
  }
  for (int i = i0; i < 1024; i += stride) {
    float bce = (i < 512) ? ebch[i] : ((i < 768) ? 0.f : ebch[i - 256]);
    ws[BENC + i] = ebih[i] + ebhh[i] + bce;
    float bcd = (i < 512) ? dbch[i] : ((i < 768) ? 0.f : dbch[i - 256]);
    ws[BDEC + i] = dbih[i] + dbhh[i] + bcd;
  }
}

__global__ __launch_bounds__(NTHR, 2) void vader_main(
    const float* __restrict__ X, const float* __restrict__ MM, const float* __restrict__ NZ,
    const float* __restrict__ Wimp,
    const float* __restrict__ aeW, const float* __restrict__ aeb,
    const float* __restrict__ adW, const float* __restrict__ adb,
    const float* __restrict__ muW, const float* __restrict__ mub,
    const float* __restrict__ stW, const float* __restrict__ stb,
    const float* __restrict__ oW, const float* __restrict__ ob,
    const float* __restrict__ mcu, const float* __restrict__ vcu, const float* __restrict__ pcu,
    float* __restrict__ ws, float* __restrict__ out) {
  const int bid = blockIdx.x, tid = threadIdx.x;
  const int mi = bid & 7, hi = bid >> 3;
  const int m_base = mi << 6;
  const int hbase = hi << 3;
  const int b0 = bid << 1;

  // ---- LDS ----
  // SINGLE CHANGE vs the 18.2ms r2 artifact: In4 f32x4 XOR-swizzle ->
  // scalar [64][65] (odd stride => b32 reads 2-way aliasing = free, m136).
  __shared__ float In_s[2][64][65];
  __shared__ __align__(16) float W_s[32][576];       // 73.7 KB resident gate-weight slice
  __shared__ __align__(16) char u1_raw[17408];       // enc: WimpT | dec: Wo_s + Xm/Mm
  __shared__ __align__(16) char u2_raw[8192];        // GateS | heads arrays | red_s
  __shared__ float C_s[64][9];
  __shared__ float Xrow_s[2][64], Mrow_s[2][64];
  __shared__ float lat_s[2][3];
  __shared__ float tot_s[5];

  float (*WimpT_s)[68] = (float(*)[68])u1_raw;
  float (*Wo_s)[260]   = (float(*)[260])u1_raw;
  float (*Xm_s)[12]    = (float(*)[12])(u1_raw + 8320);
  float (*Mm_s)[12]    = (float(*)[12])(u1_raw + 8320 + 3072);
  float* GateS         = (float*)u2_raw;
  float (*Hrow_s)[256] = (float(*)[256])u2_raw;
  float (*cc_s)[256]   = (float(*)[256])(u2_raw + 2048);
  float (*mu_s)[32]    = (float(*)[32])(u2_raw + 4096);
  float (*std_s)[32]   = (float(*)[32])(u2_raw + 4352);
  float (*z_s)[32]     = (float(*)[32])(u2_raw + 4608);
  float* red_s         = (float*)u2_raw;

  float* hbuf = ws + HBUF;
  float* cbuf = ws + CBUF;
  float* ximp = ws + XIMP;
  float* part = ws + OFF_PART;

  const int mA = tid & 31, nP = tid >> 5;
  const int n0 = nP << 1, n1 = n0 + 1;
  const int N0 = ((n0 >> 3) << 8) + hbase + (n0 & 7);
  const int N1 = ((n1 >> 3) << 8) + hbase + (n1 & 7);
  const int st_r = tid >> 3, st_c4 = tid & 7;
  const int mX = tid & 63, dX = tid >> 6;
  const int um = tid >> 3, uh = tid & 7;
  const bool mse_blk = (hi < 8);

  float ssq_acc = 0.f, msum_acc = 0.f;

  // ---------- helpers ----------
  auto stage_ld = [&](const float* src, int srd, int koff, float4& v0, float4& v1) {
    const float* bp = src + (size_t)(m_base + st_r) * srd + koff + (st_c4 << 2);
    v0 = *(const float4*)bp;
    v1 = *(const float4*)(bp + 32);
  };
  auto stage_wr = [&](int buf, float4 v0, float4 v1) {
    float* q = &In_s[buf][st_r][st_c4 << 2];
    q[0] = v0.x; q[1] = v0.y; q[2] = v0.z; q[3] = v0.w;
    q[32] = v1.x; q[33] = v1.y; q[34] = v1.z; q[35] = v1.w;
  };
  auto chunk_src_enc = [&](int ch, int t, int pp, const float*& src, int& srd, int& koff) {
    if (ch == 0)      { src = ximp + (size_t)(t & 1) * (512 * 64); srd = 64;  koff = 0; }
    else if (ch < 5)  { src = hbuf + (size_t)pp * SZ; srd = 256; koff = (ch - 1) << 6; }
    else              { src = cbuf + (size_t)pp * SZ; srd = 256; koff = (ch - 5) << 6; }
  };
  auto chunk_src_dec = [&](int ch, int pp, const float*& src, int& srd, int& koff) {
    if (ch < 4) { src = hbuf + (size_t)pp * SZ; srd = 256; koff = ch << 6; }
    else        { src = cbuf + (size_t)pp * SZ; srd = 256; koff = (ch - 4) << 6; }
  };
  auto gates_chunk = [&](int buf, int ch, float& a00, float& a01, float& a10, float& a11) {
    const float* w0p = &W_s[n0][ch << 6];
    const float* w1p = &W_s[n1][ch << 6];
    const float* i0 = In_s[buf][mA];
    const float* i1 = In_s[buf][mA + 32];
#pragma unroll
    for (int k4 = 0; k4 < 16; ++k4) {
      float4 w0 = *(const float4*)(w0p + (k4 << 2));
      float4 w1 = *(const float4*)(w1p + (k4 << 2));
      float x00 = i0[(k4 << 2) + 0], x01 = i0[(k4 << 2) + 1];
      float x02 = i0[(k4 << 2) + 2], x03 = i0[(k4 << 2) + 3];
      float x10 = i1[(k4 << 2) + 0], x11 = i1[(k4 << 2) + 1];
      float x12 = i1[(k4 << 2) + 2], x13 = i1[(k4 << 2) + 3];
      a00 = fmaf(x00, w0.x, a00); a00 = fmaf(x01, w0.y, a00);
      a00 = fmaf(x02, w0.z, a00); a00 = fmaf(x03, w0.w, a00);
      a01 = fmaf(x00, w1.x, a01); a01 = fmaf(x01, w1.y, a01);
      a01 = fmaf(x02, w1.z, a01); a01 = fmaf(x03, w1.w, a01);
      a10 = fmaf(x10, w0.x, a10); a10 = fmaf(x11, w0.y, a10);
      a10 = fmaf(x12, w0.z, a10); a10 = fmaf(x13, w0.w, a10);
      a11 = fmaf(x10, w1.x, a11); a11 = fmaf(x11, w1.y, a11);
      a11 = fmaf(x12, w1.z, a11); a11 = fmaf(x13, w1.w, a11);
    }
  };
  auto xrec_chunk = [&](int buf, int ch, float& ax) {
    const float* wp = &Wo_s[dX][ch << 6];
    const float* ir = In_s[buf][mX];
#pragma unroll
    for (int k4 = 0; k4 < 16; ++k4) {
      float4 w = *(const float4*)(wp + (k4 << 2));
      ax = fmaf(ir[(k4 << 2) + 0], w.x, ax);
      ax = fmaf(ir[(k4 << 2) + 1], w.y, ax);
      ax = fmaf(ir[(k4 << 2) + 2], w.z, ax);
      ax = fmaf(ir[(k4 << 2) + 3], w.w, ax);
    }
  };
  auto do_update = [&](float a00, float a01, float a10, float a11, float* hbo, float* cbo) {
    GateS[((n0 >> 3) << 9) + (mA << 3) + (n0 & 7)] = a00;
    GateS[((n0 >> 3) << 9) + ((mA + 32) << 3) + (n0 & 7)] = a10;
    GateS[((n1 >> 3) << 9) + (mA << 3) + (n1 & 7)] = a01;
    GateS[((n1 >> 3) << 9) + ((mA + 32) << 3) + (n1 & 7)] = a11;
    __syncthreads();
    float iv = sigm_(GateS[(0 << 9) + (um << 3) + uh]);
    float fv = sigm_(GateS[(1 << 9) + (um << 3) + uh]);
    float gv = tanhf(GateS[(2 << 9) + (um << 3) + uh]);
    float ov = sigm_(GateS[(3 << 9) + (um << 3) + uh]);
    float cold = C_s[um][uh];
    float cn = fmaf(fv, cold, iv * gv);
    float hn = ov * tanhf(cn);
    C_s[um][uh] = cn;
    size_t off = (size_t)(m_base + um) * 256 + hbase + uh;
    hbo[off] = hn;
    cbo[off] = cn;
  };
  auto produce_ximp = [&](int tn) {
    if (tid < 128) {
      int r = tid >> 6, d = tid & 63;
      Xrow_s[r][d] = X[((size_t)(b0 + r) * 256 + tn) * 64 + d];
    } else if (tid < 256) {
      int r = (tid >> 6) & 1, d = tid & 63;
      Mrow_s[r][d] = MM[((size_t)(b0 + r) * 256 + tn) * 64 + d];
    }
    __syncthreads();
    if (tid < 128) {
      int r = tid >> 6, d = tid & 63;
      float s = 0.f;
#pragma unroll 8
      for (int e = 0; e < 64; ++e) s = fmaf(Xrow_s[r][e], WimpT_s[e][d], s);
      float x = Xrow_s[r][d];
      ximp[(size_t)(tn & 1) * (512 * 64) + (size_t)(b0 + r) * 64 + d] =
          fmaf(x, Mrow_s[r][d], s * (1.f - x));
    }
  };

  // ---------- encoder phase setup ----------
  {
    int n = tid >> 4, c16 = tid & 15;
    const float* wsrc = ws + WENC + (size_t)(((n >> 3) << 8) + hbase + (n & 7)) * 576;
#pragma unroll
    for (int j = 0; j < 9; ++j) {
      int c4 = c16 * 9 + j;
      *(float4*)&W_s[n][c4 << 2] = *(const float4*)&wsrc[c4 << 2];
    }
    for (int i = tid; i < 4096; i += NTHR) {
      int d = i >> 6, e = i & 63;
      WimpT_s[e][d] = Wimp[i];
    }
    for (int i = tid; i < 576; i += NTHR) ((float*)C_s)[i] = 0.f;
  }
  float bia0 = ws[BENC + N0], bia1 = ws[BENC + N1];
  produce_ximp(0);
  gbar(ws);

  // ---------- encoder scan ----------
  int p = 0;
  for (int t = 0; t < 256; ++t) {
    float a00 = bia0, a01 = bia1, a10 = bia0, a11 = bia1;
    float4 r0, r1;
    const float* src; int srd, koff;
    chunk_src_enc(0, t, p, src, srd, koff);
    stage_ld(src, srd, koff, r0, r1);
    stage_wr(0, r0, r1);
    __syncthreads();
    for (int ch = 0; ch < 9; ++ch) {
      if (ch < 8) { chunk_src_enc(ch + 1, t, p, src, srd, koff); stage_ld(src, srd, koff, r0, r1); }
      gates_chunk(ch & 1, ch, a00, a01, a10, a11);
      if (ch < 8) stage_wr((ch + 1) & 1, r0, r1);
      __syncthreads();
    }
    do_update(a00, a01, a10, a11, hbuf + (size_t)(p ^ 1) * SZ, cbuf + (size_t)(p ^ 1) * SZ);
    if (t < 255) produce_ximp(t + 1);
    gbar(ws);
    p ^= 1;
  }
  // p == 0, c_T lives in cbuf[0]

  // ---------- AE heads + latent (row-local: rows b0,b0+1) ----------
  {
    int rr = tid >> 8, j = tid & 255;
    Hrow_s[rr][j] = cbuf[(size_t)(b0 + rr) * 256 + j];
  }
  __syncthreads();
  {
    int rr = tid >> 8, u = tid & 255;
    float a = aeb[u];
    const float4* wr = (const float4*)(aeW + (size_t)u * 256);
#pragma unroll 4
    for (int j4 = 0; j4 < 64; ++j4) {
      float4 w = wr[j4];
      a = fmaf(Hrow_s[rr][(j4 << 2) + 0], w.x, a);
      a = fmaf(Hrow_s[rr][(j4 << 2) + 1], w.y, a);
      a = fmaf(Hrow_s[rr][(j4 << 2) + 2], w.z, a);
      a = fmaf(Hrow_s[rr][(j4 << 2) + 3], w.w, a);
    }
    cc_s[rr][u] = softplus_(a);
  }
  __syncthreads();
  if (tid < 128) {
    int rr = tid >> 6, sel = (tid >> 5) & 1, q = tid & 31;
    const float* Wm = sel ? stW : muW;
    float a = sel ? stb[q] : mub[q];
    const float4* wr = (const float4*)(Wm + (size_t)q * 256);
#pragma unroll 4
    for (int j4 = 0; j4 < 64; ++j4) {
      float4 w = wr[j4];
      a = fmaf(cc_s[rr][(j4 << 2) + 0], w.x, a);
      a = fmaf(cc_s[rr][(j4 << 2) + 1], w.y, a);
      a = fmaf(cc_s[rr][(j4 << 2) + 2], w.z, a);
      a = fmaf(cc_s[rr][(j4 << 2) + 3], w.w, a);
    }
    if (sel) std_s[rr][q] = a; else mu_s[rr][q] = a;
  }
  __syncthreads();
  if (tid < 64) {
    int rr = tid >> 5, q = tid & 31;
    float zv = fmaf(expf(0.5f * std_s[rr][q]), NZ[(size_t)(b0 + rr) * 32 + q], mu_s[rr][q]);
    z_s[rr][q] = zv;
    out[1 + (size_t)(b0 + rr) * 32 + q] = zv;
  }
  __syncthreads();
  {
    int rr = tid >> 8, u = tid & 255;
    float a = adb[u];
#pragma unroll
    for (int q = 0; q < 32; ++q) a = fmaf(z_s[rr][q], adW[(size_t)u * 32 + q], a);
    hbuf[(size_t)(b0 + rr) * 256 + u] = softplus_(a);
    cbuf[(size_t)(b0 + rr) * 256 + u] = 0.f;
  }
  if (tid < 128) {
    int wv = tid >> 6, ln = tid & 63;
    if (ln < 32) {
      float zd = z_s[wv][ln], mud = mu_s[wv][ln], sdd = std_s[wv][ln];
      float vt = expf(sdd);
      float l3p = -0.5f * (1.f + sdd);
      float lp[8], tk[8];
#pragma unroll
      for (int k = 0; k < 8; ++k) {
        float vc = softplus_(vcu[(k << 5) + ln]);
        float lvc = logf(vc + EPSF);
        float mc = mcu[(k << 5) + ln];
        float dz = zd - mc;
        float a_d = lvc + LOG2PIF + dz * dz / vc;
        float ive = 1.f / (vc + EPSF);
        float dm = mud - mc;
        float t_d = lvc + fmaf(vt, ive, dm * dm * ive);
#pragma unroll
        for (int off = 16; off > 0; off >>= 1) {
          a_d += __shfl_xor(a_d, off, 64);
          t_d += __shfl_xor(t_d, off, 64);
        }
        lp[k] = -0.5f * a_d;
        tk[k] = t_d;
      }
#pragma unroll
      for (int off = 16; off > 0; off >>= 1) l3p += __shfl_xor(l3p, off, 64);
      float phv[8], mx = -1e30f;
#pragma unroll
      for (int k = 0; k < 8; ++k) { phv[k] = pcu[k]; mx = fmaxf(mx, phv[k]); }
      float se = 0.f;
#pragma unroll
      for (int k = 0; k < 8; ++k) se += expf(phv[k] - mx);
      float lphi[8], lpf[8], mx2 = -1e30f;
#pragma unroll
      for (int k = 0; k < 8; ++k) {
        lphi[k] = logf(expf(phv[k] - mx) / se + EPSF);
        lpf[k] = lphi[k] + lp[k];
        mx2 = fmaxf(mx2, lpf[k]);
      }
      float s2 = 0.f;
#pragma unroll
      for (int k = 0; k < 8; ++k) s2 += expf(lpf[k] - mx2);
      float lse = mx2 + logf(s2);
      float l1 = 0.f, l2 = 0.f;
#pragma unroll
      for (int k = 0; k < 8; ++k) {
        float lg = lpf[k] - lse;
        float gm = expf(lg);
        l1 = fmaf(gm, tk[k], l1);
        l2 = fmaf(gm, lphi[k] - lg, l2);
      }
      if (ln == 0) {
        lat_s[wv][0] = 0.5f * l1;
        lat_s[wv][1] = -l2;
        lat_s[wv][2] = l3p;
      }
    }
  }
  __syncthreads();

  // ---------- decoder phase setup ----------
  {
    int n = tid >> 4, c16 = tid & 15;
    const float* wsrc = ws + WDEC + (size_t)(((n >> 3) << 8) + hbase + (n & 7)) * 512;
#pragma unroll
    for (int j = 0; j < 8; ++j) {
      int c4 = (c16 << 3) + j;
      *(float4*)&W_s[n][c4 << 2] = *(const float4*)&wsrc[c4 << 2];
    }
    if (mse_blk) {
      int r = tid >> 6, c4 = tid & 63;
      *(float4*)&Wo_s[r][c4 << 2] = *(const float4*)&oW[(size_t)((hi << 3) + r) * 256 + (c4 << 2)];
    }
    for (int i = tid; i < 576; i += NTHR) ((float*)C_s)[i] = 0.f;
  }
  float bia0d = ws[BDEC + N0], bia1d = ws[BDEC + N1];
  float obv = mse_blk ? ob[(hi << 3) + dX] : 0.f;
  gbar(ws);

  // ---------- decoder scan (+ fused X_rec / masked MSE) ----------
  for (int t = 0; t <= 256; ++t) {
    const bool dg = (t < 256);
    const bool dm = mse_blk && (t >= 1);
    const int NC = dg ? 8 : 4;
    float a00 = bia0d, a01 = bia1d, a10 = bia0d, a11 = bia1d;
    float ax = 0.f;
    float4 r0, r1;
    const float* src; int srd, koff;
    chunk_src_dec(0, p, src, srd, koff);
    stage_ld(src, srd, koff, r0, r1);
    stage_wr(0, r0, r1);
    if (dm) {
      if (tid < 128) {
        int r2 = tid >> 1, hf = tid & 1;
        *(float4*)&Xm_s[r2][hf << 2] =
            *(const float4*)&X[((size_t)(m_base + r2) * 256 + (t - 1)) * 64 + (hi << 3) + (hf << 2)];
      } else if (tid < 256) {
        int r2 = (tid - 128) >> 1, hf = tid & 1;
        *(float4*)&Mm_s[r2][hf << 2] =
            *(const float4*)&MM[((size_t)(m_base + r2) * 256 + (t - 1)) * 64 + (hi << 3) + (hf << 2)];
      }
    }
    __syncthreads();
    for (int ch = 0; ch < NC; ++ch) {
      if (ch + 1 < NC) { chunk_src_dec(ch + 1, p, src, srd, koff); stage_ld(src, srd, koff, r0, r1); }
      if (dg) gates_chunk(ch & 1, ch, a00, a01, a10, a11);
      if (dm && ch < 4) xrec_chunk(ch & 1, ch, ax);
      if (ch + 1 < NC) stage_wr((ch + 1) & 1, r0, r1);
      __syncthreads();
    }
    if (dm) {
      float xr = ax + obv;
      float df = xr - Xm_s[mX][dX];
      float mv = Mm_s[mX][dX];
      ssq_acc = fmaf(mv, df * df, ssq_acc);
      msum_acc += mv;
    }
    if (dg) {
      do_update(a00, a01, a10, a11, hbuf + (size_t)(p ^ 1) * SZ, cbuf + (size_t)(p ^ 1) * SZ);
      gbar(ws);
      p ^= 1;
    }
  }

  // ---------- per-block partials ----------
  red_s[tid] = ssq_acc;
  __syncthreads();
  for (int s = 256; s > 0; s >>= 1) { if (tid < s) red_s[tid] += red_s[tid + s]; __syncthreads(); }
  if (tid == 0) part[(bid << 3) + 0] = red_s[0];
  __syncthreads();
  red_s[tid] = msum_acc;
  __syncthreads();
  for (int s = 256; s > 0; s >>= 1) { if (tid < s) red_s[tid] += red_s[tid + s]; __syncthreads(); }
  if (tid == 0) {
    part[(bid << 3) + 1] = red_s[0];
    part[(bid << 3) + 2] = lat_s[0][0] + lat_s[1][0];
    part[(bid << 3) + 3] = lat_s[0][1] + lat_s[1][1];
    part[(bid << 3) + 4] = lat_s[0][2] + lat_s[1][2];
  }
  gbar(ws);

  // ---------- final reduce + loss (block 0) ----------
  if (bid == 0) {
    for (int c = 0; c < 5; ++c) {
      red_s[tid] = (tid < 256) ? part[(tid << 3) + c] : 0.f;
      __syncthreads();
      for (int s = 256; s > 0; s >>= 1) { if (tid < s) red_s[tid] += red_s[tid + s]; __syncthreads(); }
      if (tid == 0) tot_s[c] = red_s[0];
      __syncthreads();
    }
    if (tid == 0) {
      float ssq = tot_s[0], msum = tot_s[1];
      float mse = ssq / (msum + 1e-12f);
      float recon = mse * 16384.f / msum;
      float latent = (tot_s[2] + tot_s[3] + tot_s[4]) / 512.f;
      out[0] = recon + latent;
    }
  }
}

extern "C" void kernel_launch(void* const* d_in, const int* in_sizes, int n_in,
                              void* d_out, int out_size, void* d_ws, size_t ws_size,
                              hipStream_t stream) {
  (void)in_sizes; (void)out_size;
  if (n_in < 29) return;
  if (ws_size < WS_NEED * sizeof(float)) return;
  const float* X    = (const float*)d_in[0];
  const float* MM   = (const float*)d_in[1];
  const float* NZ   = (const float*)d_in[2];
  const float* Wimp = (const float*)d_in[3];
  const float* eWih = (const float*)d_in[4];
  const float* ebih = (const float*)d_in[5];
  const float* eWhh = (const float*)d_in[6];
  const float* ebhh = (const float*)d_in[7];
  const float* eWch = (const float*)d_in[8];
  const float* ebch = (const float*)d_in[9];
  const float* dbih = (const float*)d_in[11];
  const float* dWhh = (const float*)d_in[12];
  const float* dbhh = (const float*)d_in[13];
  const float* dWch = (const float*)d_in[14];
  const float* dbch = (const float*)d_in[15];
  const float* aeW  = (const float*)d_in[16];
  const float* aeb  = (const float*)d_in[17];
  const float* adW  = (const float*)d_in[18];
  const float* adb  = (const float*)d_in[19];
  const float* muW  = (const float*)d_in[20];
  const float* mub  = (const float*)d_in[21];
  const float* stW  = (const float*)d_in[22];
  const float* stb  = (const float*)d_in[23];
  const float* oW   = (const float*)d_in[24];
  const float* ob   = (const float*)d_in[25];
  const float* mcu  = (const float*)d_in[26];
  const float* vcu  = (const float*)d_in[27];
  const float* pcu  = (const float*)d_in[28];
  float* ws = (float*)d_ws;

  vader_init<<<512, 256, 0, stream>>>(eWih, ebih, eWhh, ebhh, eWch, ebch,
                                      dbih, dWhh, dbhh, dWch, dbch, ws);
  vader_main<<<NBLK, NTHR, 0, stream>>>(X, MM, NZ, Wimp, aeW, aeb, adW, adb,
                                        muW, mub, stW, stb, oW, ob, mcu, vcu, pcu,
                                        ws, (float*)d_out);
}

// Round 11
// 16458.424 us; speedup vs baseline: 9.6455x; 1.1099x over previous
//
#include <hip/hip_runtime.h>
#include <math.h>

#define NBLK 256
#define NTHR 512

constexpr float EPSF = 1e-9f;
constexpr float LOG2PIF = 1.8378770664093453f;

// ---- workspace layout (float offsets) ----
constexpr size_t OFF_CNT  = 0;
constexpr size_t OFF_GEN  = 32;
constexpr size_t OFF_PART = 128;
constexpr size_t WENC = 4096;                        // [1024][576]
constexpr size_t BENC = WENC + (size_t)1024 * 576;   // [1024]
constexpr size_t WDEC = BENC + 1024;                 // [1024][512]
constexpr size_t BDEC = WDEC + (size_t)1024 * 512;   // [1024]
constexpr size_t HBUF = BDEC + 1024;                 // [2][512][256]
constexpr size_t CBUF = HBUF + (size_t)2 * 512 * 256;
constexpr size_t XIMP = CBUF + (size_t)2 * 512 * 256; // [2][512][64]
constexpr size_t WS_NEED = XIMP + (size_t)2 * 512 * 64;

constexpr size_t SZ = (size_t)512 * 256;

__device__ __forceinline__ float sigm_(float x) { return 1.f / (1.f + expf(-x)); }
__device__ __forceinline__ float softplus_(float x) { return x > 20.f ? x : log1pf(expf(x)); }

__device__ __forceinline__ void gbar(float* ws) {
  __syncthreads();
  if (threadIdx.x == 0) {
    __threadfence();
    unsigned* cnt = (unsigned*)(ws + OFF_CNT);
    unsigned* gen = (unsigned*)(ws + OFF_GEN);
    unsigned g = __hip_atomic_load(gen, __ATOMIC_RELAXED, __HIP_MEMORY_SCOPE_AGENT);
    unsigned a = __hip_atomic_fetch_add(cnt, 1u, __ATOMIC_ACQ_REL, __HIP_MEMORY_SCOPE_AGENT);
    if (a == NBLK - 1) {
      __hip_atomic_store(cnt, 0u, __ATOMIC_RELAXED, __HIP_MEMORY_SCOPE_AGENT);
      __hip_atomic_store(gen, g + 1u, __ATOMIC_RELEASE, __HIP_MEMORY_SCOPE_AGENT);
    } else {
      while (__hip_atomic_load(gen, __ATOMIC_RELAXED, __HIP_MEMORY_SCOPE_AGENT) == g) {
        __builtin_amdgcn_s_sleep(2);
      }
    }
    __threadfence();
  }
  __syncthreads();
}

__global__ void vader_init(
    const float* __restrict__ eWih, const float* __restrict__ ebih,
    const float* __restrict__ eWhh, const float* __restrict__ ebhh,
    const float* __restrict__ eWch, const float* __restrict__ ebch,
    const float* __restrict__ dbih, const float* __restrict__ dWhh,
    const float* __restrict__ dbhh, const float* __restrict__ dWch,
    const float* __restrict__ dbch, float* __restrict__ ws) {
  const int i0 = blockIdx.x * blockDim.x + threadIdx.x;
  const int stride = gridDim.x * blockDim.x;
  for (int i = i0; i < 4096; i += stride) ws[i] = 0.f;
  for (int i = i0; i < 512 * 256; i += stride) {
    ws[HBUF + i] = 0.f;
    ws[CBUF + i] = 0.f;
  }
  for (int i = i0; i < 1024 * 576; i += stride) {
    int n = i / 576, k = i - n * 576;
    float v;
    if (k < 64)       v = eWih[n * 64 + k];
    else if (k < 320) v = eWhh[n * 256 + (k - 64)];
    else {
      int j = k - 320;
      if (n < 512)      v = eWch[n * 256 + j];
      else if (n < 768) v = 0.f;
      else              v = eWch[(n - 256) * 256 + j];
    }
    ws[WENC + i] = v;
  }
  for (int i = i0; i < 1024 * 512; i += stride) {
    int n = i >> 9, k = i & 511;
    float v;
    if (k < 256) v = dWhh[n * 256 + k];
    else {
      int j = k - 256;
      if (n < 512)      v = dWch[n * 256 + j];
      else if (n < 768) v = 0.f;
      else              v = dWch[(n - 256) * 256 + j];
    }
    ws[WDEC + i] = v;
  }
  for (int i = i0; i < 1024; i += stride) {
    float bce = (i < 512) ? ebch[i] : ((i < 768) ? 0.f : ebch[i - 256]);
    ws[BENC + i] = ebih[i] + ebhh[i] + bce;
    float bcd = (i < 512) ? dbch[i] : ((i < 768) ? 0.f : dbch[i - 256]);
    ws[BDEC + i] = dbih[i] + dbhh[i] + bcd;
  }
}

__global__ __launch_bounds__(NTHR, 2) void vader_main(
    const float* __restrict__ X, const float* __restrict__ MM, const float* __restrict__ NZ,
    const float* __restrict__ Wimp,
    const float* __restrict__ aeW, const float* __restrict__ aeb,
    const float* __restrict__ adW, const float* __restrict__ adb,
    const float* __restrict__ muW, const float* __restrict__ mub,
    const float* __restrict__ stW, const float* __restrict__ stb,
    const float* __restrict__ oW, const float* __restrict__ ob,
    const float* __restrict__ mcu, const float* __restrict__ vcu, const float* __restrict__ pcu,
    float* __restrict__ ws, float* __restrict__ out) {
  const int bid = blockIdx.x, tid = threadIdx.x;
  const int mi = bid & 7, hi = bid >> 3;
  const int m_base = mi << 6;
  const int hbase = hi << 3;
  const int b0 = bid << 1;

  // ---- LDS ----
  // SINGLE CHANGE vs r10 (18.27ms): row stride 65 -> 68 (272B = 17*16, so
  // &In_s[r][4k] is 16B-aligned -> ds_read_b128/ds_write_b128, and bank
  // group (17r+k) % 8 spreads 64 lanes 8-per-group = conflict-free).
  // Cuts In-side LDS instructions 4x (128 b32 -> 32 b128 per chunk).
  __shared__ __align__(16) float In_s[2][64][68];
  __shared__ __align__(16) float W_s[32][576];       // 73.7 KB resident gate-weight slice
  __shared__ __align__(16) char u1_raw[17408];       // enc: WimpT | dec: Wo_s + Xm/Mm
  __shared__ __align__(16) char u2_raw[8192];        // GateS | heads arrays | red_s
  __shared__ float C_s[64][9];
  __shared__ float Xrow_s[2][64], Mrow_s[2][64];
  __shared__ float lat_s[2][3];
  __shared__ float tot_s[5];

  float (*WimpT_s)[68] = (float(*)[68])u1_raw;
  float (*Wo_s)[260]   = (float(*)[260])u1_raw;
  float (*Xm_s)[12]    = (float(*)[12])(u1_raw + 8320);
  float (*Mm_s)[12]    = (float(*)[12])(u1_raw + 8320 + 3072);
  float* GateS         = (float*)u2_raw;
  float (*Hrow_s)[256] = (float(*)[256])u2_raw;
  float (*cc_s)[256]   = (float(*)[256])(u2_raw + 2048);
  float (*mu_s)[32]    = (float(*)[32])(u2_raw + 4096);
  float (*std_s)[32]   = (float(*)[32])(u2_raw + 4352);
  float (*z_s)[32]     = (float(*)[32])(u2_raw + 4608);
  float* red_s         = (float*)u2_raw;

  float* hbuf = ws + HBUF;
  float* cbuf = ws + CBUF;
  float* ximp = ws + XIMP;
  float* part = ws + OFF_PART;

  const int mA = tid & 31, nP = tid >> 5;
  const int n0 = nP << 1, n1 = n0 + 1;
  const int N0 = ((n0 >> 3) << 8) + hbase + (n0 & 7);
  const int N1 = ((n1 >> 3) << 8) + hbase + (n1 & 7);
  const int st_r = tid >> 3, st_c4 = tid & 7;
  const int mX = tid & 63, dX = tid >> 6;
  const int um = tid >> 3, uh = tid & 7;
  const bool mse_blk = (hi < 8);

  float ssq_acc = 0.f, msum_acc = 0.f;

  // ---------- helpers ----------
  auto stage_ld = [&](const float* src, int srd, int koff, float4& v0, float4& v1) {
    const float* bp = src + (size_t)(m_base + st_r) * srd + koff + (st_c4 << 2);
    v0 = *(const float4*)bp;
    v1 = *(const float4*)(bp + 32);
  };
  auto stage_wr = [&](int buf, float4 v0, float4 v1) {
    float* q = &In_s[buf][st_r][st_c4 << 2];
    *(float4*)q = v0;
    *(float4*)(q + 32) = v1;
  };
  auto chunk_src_enc = [&](int ch, int t, int pp, const float*& src, int& srd, int& koff) {
    if (ch == 0)      { src = ximp + (size_t)(t & 1) * (512 * 64); srd = 64;  koff = 0; }
    else if (ch < 5)  { src = hbuf + (size_t)pp * SZ; srd = 256; koff = (ch - 1) << 6; }
    else              { src = cbuf + (size_t)pp * SZ; srd = 256; koff = (ch - 5) << 6; }
  };
  auto chunk_src_dec = [&](int ch, int pp, const float*& src, int& srd, int& koff) {
    if (ch < 4) { src = hbuf + (size_t)pp * SZ; srd = 256; koff = ch << 6; }
    else        { src = cbuf + (size_t)pp * SZ; srd = 256; koff = (ch - 4) << 6; }
  };
  auto gates_chunk = [&](int buf, int ch, float& a00, float& a01, float& a10, float& a11) {
    const float* w0p = &W_s[n0][ch << 6];
    const float* w1p = &W_s[n1][ch << 6];
#pragma unroll
    for (int k4 = 0; k4 < 16; ++k4) {
      float4 w0 = *(const float4*)(w0p + (k4 << 2));
      float4 w1 = *(const float4*)(w1p + (k4 << 2));
      float4 a0 = *(const float4*)&In_s[buf][mA][k4 << 2];
      float4 a1 = *(const float4*)&In_s[buf][mA + 32][k4 << 2];
      a00 = fmaf(a0.x, w0.x, a00); a00 = fmaf(a0.y, w0.y, a00);
      a00 = fmaf(a0.z, w0.z, a00); a00 = fmaf(a0.w, w0.w, a00);
      a01 = fmaf(a0.x, w1.x, a01); a01 = fmaf(a0.y, w1.y, a01);
      a01 = fmaf(a0.z, w1.z, a01); a01 = fmaf(a0.w, w1.w, a01);
      a10 = fmaf(a1.x, w0.x, a10); a10 = fmaf(a1.y, w0.y, a10);
      a10 = fmaf(a1.z, w0.z, a10); a10 = fmaf(a1.w, w0.w, a10);
      a11 = fmaf(a1.x, w1.x, a11); a11 = fmaf(a1.y, w1.y, a11);
      a11 = fmaf(a1.z, w1.z, a11); a11 = fmaf(a1.w, w1.w, a11);
    }
  };
  auto xrec_chunk = [&](int buf, int ch, float& ax) {
    const float* wp = &Wo_s[dX][ch << 6];
#pragma unroll
    for (int k4 = 0; k4 < 16; ++k4) {
      float4 w = *(const float4*)(wp + (k4 << 2));
      float4 av = *(const float4*)&In_s[buf][mX][k4 << 2];
      ax = fmaf(av.x, w.x, ax);
      ax = fmaf(av.y, w.y, ax);
      ax = fmaf(av.z, w.z, ax);
      ax = fmaf(av.w, w.w, ax);
    }
  };
  auto do_update = [&](float a00, float a01, float a10, float a11, float* hbo, float* cbo) {
    GateS[((n0 >> 3) << 9) + (mA << 3) + (n0 & 7)] = a00;
    GateS[((n0 >> 3) << 9) + ((mA + 32) << 3) + (n0 & 7)] = a10;
    GateS[((n1 >> 3) << 9) + (mA << 3) + (n1 & 7)] = a01;
    GateS[((n1 >> 3) << 9) + ((mA + 32) << 3) + (n1 & 7)] = a11;
    __syncthreads();
    float iv = sigm_(GateS[(0 << 9) + (um << 3) + uh]);
    float fv = sigm_(GateS[(1 << 9) + (um << 3) + uh]);
    float gv = tanhf(GateS[(2 << 9) + (um << 3) + uh]);
    float ov = sigm_(GateS[(3 << 9) + (um << 3) + uh]);
    float cold = C_s[um][uh];
    float cn = fmaf(fv, cold, iv * gv);
    float hn = ov * tanhf(cn);
    C_s[um][uh] = cn;
    size_t off = (size_t)(m_base + um) * 256 + hbase + uh;
    hbo[off] = hn;
    cbo[off] = cn;
  };
  auto produce_ximp = [&](int tn) {
    if (tid < 128) {
      int r = tid >> 6, d = tid & 63;
      Xrow_s[r][d] = X[((size_t)(b0 + r) * 256 + tn) * 64 + d];
    } else if (tid < 256) {
      int r = (tid >> 6) & 1, d = tid & 63;
      Mrow_s[r][d] = MM[((size_t)(b0 + r) * 256 + tn) * 64 + d];
    }
    __syncthreads();
    if (tid < 128) {
      int r = tid >> 6, d = tid & 63;
      float s = 0.f;
#pragma unroll 8
      for (int e = 0; e < 64; ++e) s = fmaf(Xrow_s[r][e], WimpT_s[e][d], s);
      float x = Xrow_s[r][d];
      ximp[(size_t)(tn & 1) * (512 * 64) + (size_t)(b0 + r) * 64 + d] =
          fmaf(x, Mrow_s[r][d], s * (1.f - x));
    }
  };

  // ---------- encoder phase setup ----------
  {
    int n = tid >> 4, c16 = tid & 15;
    const float* wsrc = ws + WENC + (size_t)(((n >> 3) << 8) + hbase + (n & 7)) * 576;
#pragma unroll
    for (int j = 0; j < 9; ++j) {
      int c4 = c16 * 9 + j;
      *(float4*)&W_s[n][c4 << 2] = *(const float4*)&wsrc[c4 << 2];
    }
    for (int i = tid; i < 4096; i += NTHR) {
      int d = i >> 6, e = i & 63;
      WimpT_s[e][d] = Wimp[i];
    }
    for (int i = tid; i < 576; i += NTHR) ((float*)C_s)[i] = 0.f;
  }
  float bia0 = ws[BENC + N0], bia1 = ws[BENC + N1];
  produce_ximp(0);
  gbar(ws);

  // ---------- encoder scan ----------
  int p = 0;
  for (int t = 0; t < 256; ++t) {
    float a00 = bia0, a01 = bia1, a10 = bia0, a11 = bia1;
    float4 r0, r1;
    const float* src; int srd, koff;
    chunk_src_enc(0, t, p, src, srd, koff);
    stage_ld(src, srd, koff, r0, r1);
    stage_wr(0, r0, r1);
    __syncthreads();
    for (int ch = 0; ch < 9; ++ch) {
      if (ch < 8) { chunk_src_enc(ch + 1, t, p, src, srd, koff); stage_ld(src, srd, koff, r0, r1); }
      gates_chunk(ch & 1, ch, a00, a01, a10, a11);
      if (ch < 8) stage_wr((ch + 1) & 1, r0, r1);
      __syncthreads();
    }
    do_update(a00, a01, a10, a11, hbuf + (size_t)(p ^ 1) * SZ, cbuf + (size_t)(p ^ 1) * SZ);
    if (t < 255) produce_ximp(t + 1);
    gbar(ws);
    p ^= 1;
  }
  // p == 0, c_T lives in cbuf[0]

  // ---------- AE heads + latent (row-local: rows b0,b0+1) ----------
  {
    int rr = tid >> 8, j = tid & 255;
    Hrow_s[rr][j] = cbuf[(size_t)(b0 + rr) * 256 + j];
  }
  __syncthreads();
  {
    int rr = tid >> 8, u = tid & 255;
    float a = aeb[u];
    const float4* wr = (const float4*)(aeW + (size_t)u * 256);
#pragma unroll 4
    for (int j4 = 0; j4 < 64; ++j4) {
      float4 w = wr[j4];
      a = fmaf(Hrow_s[rr][(j4 << 2) + 0], w.x, a);
      a = fmaf(Hrow_s[rr][(j4 << 2) + 1], w.y, a);
      a = fmaf(Hrow_s[rr][(j4 << 2) + 2], w.z, a);
      a = fmaf(Hrow_s[rr][(j4 << 2) + 3], w.w, a);
    }
    cc_s[rr][u] = softplus_(a);
  }
  __syncthreads();
  if (tid < 128) {
    int rr = tid >> 6, sel = (tid >> 5) & 1, q = tid & 31;
    const float* Wm = sel ? stW : muW;
    float a = sel ? stb[q] : mub[q];
    const float4* wr = (const float4*)(Wm + (size_t)q * 256);
#pragma unroll 4
    for (int j4 = 0; j4 < 64; ++j4) {
      float4 w = wr[j4];
      a = fmaf(cc_s[rr][(j4 << 2) + 0], w.x, a);
      a = fmaf(cc_s[rr][(j4 << 2) + 1], w.y, a);
      a = fmaf(cc_s[rr][(j4 << 2) + 2], w.z, a);
      a = fmaf(cc_s[rr][(j4 << 2) + 3], w.w, a);
    }
    if (sel) std_s[rr][q] = a; else mu_s[rr][q] = a;
  }
  __syncthreads();
  if (tid < 64) {
    int rr = tid >> 5, q = tid & 31;
    float zv = fmaf(expf(0.5f * std_s[rr][q]), NZ[(size_t)(b0 + rr) * 32 + q], mu_s[rr][q]);
    z_s[rr][q] = zv;
    out[1 + (size_t)(b0 + rr) * 32 + q] = zv;
  }
  __syncthreads();
  {
    int rr = tid >> 8, u = tid & 255;
    float a = adb[u];
#pragma unroll
    for (int q = 0; q < 32; ++q) a = fmaf(z_s[rr][q], adW[(size_t)u * 32 + q], a);
    hbuf[(size_t)(b0 + rr) * 256 + u] = softplus_(a);
    cbuf[(size_t)(b0 + rr) * 256 + u] = 0.f;
  }
  if (tid < 128) {
    int wv = tid >> 6, ln = tid & 63;
    if (ln < 32) {
      float zd = z_s[wv][ln], mud = mu_s[wv][ln], sdd = std_s[wv][ln];
      float vt = expf(sdd);
      float l3p = -0.5f * (1.f + sdd);
      float lp[8], tk[8];
#pragma unroll
      for (int k = 0; k < 8; ++k) {
        float vc = softplus_(vcu[(k << 5) + ln]);
        float lvc = logf(vc + EPSF);
        float mc = mcu[(k << 5) + ln];
        float dz = zd - mc;
        float a_d = lvc + LOG2PIF + dz * dz / vc;
        float ive = 1.f / (vc + EPSF);
        float dm = mud - mc;
        float t_d = lvc + fmaf(vt, ive, dm * dm * ive);
#pragma unroll
        for (int off = 16; off > 0; off >>= 1) {
          a_d += __shfl_xor(a_d, off, 64);
          t_d += __shfl_xor(t_d, off, 64);
        }
        lp[k] = -0.5f * a_d;
        tk[k] = t_d;
      }
#pragma unroll
      for (int off = 16; off > 0; off >>= 1) l3p += __shfl_xor(l3p, off, 64);
      float phv[8], mx = -1e30f;
#pragma unroll
      for (int k = 0; k < 8; ++k) { phv[k] = pcu[k]; mx = fmaxf(mx, phv[k]); }
      float se = 0.f;
#pragma unroll
      for (int k = 0; k < 8; ++k) se += expf(phv[k] - mx);
      float lphi[8], lpf[8], mx2 = -1e30f;
#pragma unroll
      for (int k = 0; k < 8; ++k) {
        lphi[k] = logf(expf(phv[k] - mx) / se + EPSF);
        lpf[k] = lphi[k] + lp[k];
        mx2 = fmaxf(mx2, lpf[k]);
      }
      float s2 = 0.f;
#pragma unroll
      for (int k = 0; k < 8; ++k) s2 += expf(lpf[k] - mx2);
      float lse = mx2 + logf(s2);
      float l1 = 0.f, l2 = 0.f;
#pragma unroll
      for (int k = 0; k < 8; ++k) {
        float lg = lpf[k] - lse;
        float gm = expf(lg);
        l1 = fmaf(gm, tk[k], l1);
        l2 = fmaf(gm, lphi[k] - lg, l2);
      }
      if (ln == 0) {
        lat_s[wv][0] = 0.5f * l1;
        lat_s[wv][1] = -l2;
        lat_s[wv][2] = l3p;
      }
    }
  }
  __syncthreads();

  // ---------- decoder phase setup ----------
  {
    int n = tid >> 4, c16 = tid & 15;
    const float* wsrc = ws + WDEC + (size_t)(((n >> 3) << 8) + hbase + (n & 7)) * 512;
#pragma unroll
    for (int j = 0; j < 8; ++j) {
      int c4 = (c16 << 3) + j;
      *(float4*)&W_s[n][c4 << 2] = *(const float4*)&wsrc[c4 << 2];
    }
    if (mse_blk) {
      int r = tid >> 6, c4 = tid & 63;
      *(float4*)&Wo_s[r][c4 << 2] = *(const float4*)&oW[(size_t)((hi << 3) + r) * 256 + (c4 << 2)];
    }
    for (int i = tid; i < 576; i += NTHR) ((float*)C_s)[i] = 0.f;
  }
  float bia0d = ws[BDEC + N0], bia1d = ws[BDEC + N1];
  float obv = mse_blk ? ob[(hi << 3) + dX] : 0.f;
  gbar(ws);

  // ---------- decoder scan (+ fused X_rec / masked MSE) ----------
  for (int t = 0; t <= 256; ++t) {
    const bool dg = (t < 256);
    const bool dm = mse_blk && (t >= 1);
    const int NC = dg ? 8 : 4;
    float a00 = bia0d, a01 = bia1d, a10 = bia0d, a11 = bia1d;
    float ax = 0.f;
    float4 r0, r1;
    const float* src; int srd, koff;
    chunk_src_dec(0, p, src, srd, koff);
    stage_ld(src, srd, koff, r0, r1);
    stage_wr(0, r0, r1);
    if (dm) {
      if (tid < 128) {
        int r2 = tid >> 1, hf = tid & 1;
        *(float4*)&Xm_s[r2][hf << 2] =
            *(const float4*)&X[((size_t)(m_base + r2) * 256 + (t - 1)) * 64 + (hi << 3) + (hf << 2)];
      } else if (tid < 256) {
        int r2 = (tid - 128) >> 1, hf = tid & 1;
        *(float4*)&Mm_s[r2][hf << 2] =
            *(const float4*)&MM[((size_t)(m_base + r2) * 256 + (t - 1)) * 64 + (hi << 3) + (hf << 2)];
      }
    }
    __syncthreads();
    for (int ch = 0; ch < NC; ++ch) {
      if (ch + 1 < NC) { chunk_src_dec(ch + 1, p, src, srd, koff); stage_ld(src, srd, koff, r0, r1); }
      if (dg) gates_chunk(ch & 1, ch, a00, a01, a10, a11);
      if (dm && ch < 4) xrec_chunk(ch & 1, ch, ax);
      if (ch + 1 < NC) stage_wr((ch + 1) & 1, r0, r1);
      __syncthreads();
    }
    if (dm) {
      float xr = ax + obv;
      float df = xr - Xm_s[mX][dX];
      float mv = Mm_s[mX][dX];
      ssq_acc = fmaf(mv, df * df, ssq_acc);
      msum_acc += mv;
    }
    if (dg) {
      do_update(a00, a01, a10, a11, hbuf + (size_t)(p ^ 1) * SZ, cbuf + (size_t)(p ^ 1) * SZ);
      gbar(ws);
      p ^= 1;
    }
  }

  // ---------- per-block partials ----------
  red_s[tid] = ssq_acc;
  __syncthreads();
  for (int s = 256; s > 0; s >>= 1) { if (tid < s) red_s[tid] += red_s[tid + s]; __syncthreads(); }
  if (tid == 0) part[(bid << 3) + 0] = red_s[0];
  __syncthreads();
  red_s[tid] = msum_acc;
  __syncthreads();
  for (int s = 256; s > 0; s >>= 1) { if (tid < s) red_s[tid] += red_s[tid + s]; __syncthreads(); }
  if (tid == 0) {
    part[(bid << 3) + 1] = red_s[0];
    part[(bid << 3) + 2] = lat_s[0][0] + lat_s[1][0];
    part[(bid << 3) + 3] = lat_s[0][1] + lat_s[1][1];
    part[(bid << 3) + 4] = lat_s[0][2] + lat_s[1][2];
  }
  gbar(ws);

  // ---------- final reduce + loss (block 0) ----------
  if (bid == 0) {
    for (int c = 0; c < 5; ++c) {
      red_s[tid] = (tid < 256) ? part[(tid << 3) + c] : 0.f;
      __syncthreads();
      for (int s = 256; s > 0; s >>= 1) { if (tid < s) red_s[tid] += red_s[tid + s]; __syncthreads(); }
      if (tid == 0) tot_s[c] = red_s[0];
      __syncthreads();
    }
    if (tid == 0) {
      float ssq = tot_s[0], msum = tot_s[1];
      float mse = ssq / (msum + 1e-12f);
      float recon = mse * 16384.f / msum;
      float latent = (tot_s[2] + tot_s[3] + tot_s[4]) / 512.f;
      out[0] = recon + latent;
    }
  }
}

extern "C" void kernel_launch(void* const* d_in, const int* in_sizes, int n_in,
                              void* d_out, int out_size, void* d_ws, size_t ws_size,
                              hipStream_t stream) {
  (void)in_sizes; (void)out_size;
  if (n_in < 29) return;
  if (ws_size < WS_NEED * sizeof(float)) return;
  const float* X    = (const float*)d_in[0];
  const float* MM   = (const float*)d_in[1];
  const float* NZ   = (const float*)d_in[2];
  const float* Wimp = (const float*)d_in[3];
  const float* eWih = (const float*)d_in[4];
  const float* ebih = (const float*)d_in[5];
  const float* eWhh = (const float*)d_in[6];
  const float* ebhh = (const float*)d_in[7];
  const float* eWch = (const float*)d_in[8];
  const float* ebch = (const float*)d_in[9];
  const float* dbih = (const float*)d_in[11];
  const float* dWhh = (const float*)d_in[12];
  const float* dbhh = (const float*)d_in[13];
  const float* dWch = (const float*)d_in[14];
  const float* dbch = (const float*)d_in[15];
  const float* aeW  = (const float*)d_in[16];
  const float* aeb  = (const float*)d_in[17];
  const float* adW  = (const float*)d_in[18];
  const float* adb  = (const float*)d_in[19];
  const float* muW  = (const float*)d_in[20];
  const float* mub  = (const float*)d_in[21];
  const float* stW  = (const float*)d_in[22];
  const float* stb  = (const float*)d_in[23];
  const float* oW   = (const float*)d_in[24];
  const float* ob   = (const float*)d_in[25];
  const float* mcu  = (const float*)d_in[26];
  const float* vcu  = (const float*)d_in[27];
  const float* pcu  = (const float*)d_in[28];
  float* ws = (float*)d_ws;

  vader_init<<<512, 256, 0, stream>>>(eWih, ebih, eWhh, ebhh, eWch, ebch,
                                      dbih, dWhh, dbhh, dWch, dbch, ws);
  vader_main<<<NBLK, NTHR, 0, stream>>>(X, MM, NZ, Wimp, aeW, aeb, adW, adb,
                                        muW, mub, stW, stb, oW, ob, mcu, vcu, pcu,
                                        ws, (float*)d_out);
}

// Round 12
// 15756.279 us; speedup vs baseline: 10.0753x; 1.0446x over previous
//
#include <hip/hip_runtime.h>
#include <math.h>

#define NBLK 256
#define NTHR 512

constexpr float EPSF = 1e-9f;
constexpr float LOG2PIF = 1.8378770664093453f;

// ---- workspace layout (float offsets) ----
// Group barriers: cnt[mi] at mi*32 (floats 0..255), gen[mi] at 256+mi*32
// (floats 256..511). Full barrier: cnt at 512, gen at 544. Partials at 1024.
constexpr size_t OFF_GCNT = 0;
constexpr size_t OFF_GGEN = 256;
constexpr size_t OFF_FCNT = 512;
constexpr size_t OFF_FGEN = 544;
constexpr size_t OFF_PART = 1024;   // 256 * 8 floats
constexpr size_t WENC = 4096;                        // [1024][576]
constexpr size_t BENC = WENC + (size_t)1024 * 576;   // [1024]
constexpr size_t WDEC = BENC + 1024;                 // [1024][512]
constexpr size_t BDEC = WDEC + (size_t)1024 * 512;   // [1024]
constexpr size_t HBUF = BDEC + 1024;                 // [2][512][256]
constexpr size_t CBUF = HBUF + (size_t)2 * 512 * 256;
constexpr size_t XIMP = CBUF + (size_t)2 * 512 * 256; // [2][512][64]
constexpr size_t WS_NEED = XIMP + (size_t)2 * 512 * 64;

constexpr size_t SZ = (size_t)512 * 256;

__device__ __forceinline__ float sigm_(float x) { return 1.f / (1.f + expf(-x)); }
__device__ __forceinline__ float softplus_(float x) { return x > 20.f ? x : log1pf(expf(x)); }

// Group barrier: 32 blocks sharing mi. Same proven algorithm as the r2/r10/r11
// 256-block gbar (threadfence + acq_rel arrival + release flip + relaxed spin),
// only the membership (static, from bid) and count changed. 8 instances run
// independently -> 8x less same-line atomic serialization per step.
__device__ __forceinline__ void gbar_g(float* ws, int mi) {
  __syncthreads();
  if (threadIdx.x == 0) {
    __threadfence();
    unsigned* cnt = (unsigned*)(ws + OFF_GCNT + ((size_t)mi << 5));
    unsigned* gen = (unsigned*)(ws + OFF_GGEN + ((size_t)mi << 5));
    unsigned g = __hip_atomic_load(gen, __ATOMIC_RELAXED, __HIP_MEMORY_SCOPE_AGENT);
    unsigned a = __hip_atomic_fetch_add(cnt, 1u, __ATOMIC_ACQ_REL, __HIP_MEMORY_SCOPE_AGENT);
    if (a == 31u) {
      __hip_atomic_store(cnt, 0u, __ATOMIC_RELAXED, __HIP_MEMORY_SCOPE_AGENT);
      __hip_atomic_store(gen, g + 1u, __ATOMIC_RELEASE, __HIP_MEMORY_SCOPE_AGENT);
    } else {
      while (__hip_atomic_load(gen, __ATOMIC_RELAXED, __HIP_MEMORY_SCOPE_AGENT) == g) {
        __builtin_amdgcn_s_sleep(2);
      }
    }
    __threadfence();
  }
  __syncthreads();
}

// Full 256-block barrier (used once, before the final loss reduce).
__device__ __forceinline__ void gbar_full(float* ws) {
  __syncthreads();
  if (threadIdx.x == 0) {
    __threadfence();
    unsigned* cnt = (unsigned*)(ws + OFF_FCNT);
    unsigned* gen = (unsigned*)(ws + OFF_FGEN);
    unsigned g = __hip_atomic_load(gen, __ATOMIC_RELAXED, __HIP_MEMORY_SCOPE_AGENT);
    unsigned a = __hip_atomic_fetch_add(cnt, 1u, __ATOMIC_ACQ_REL, __HIP_MEMORY_SCOPE_AGENT);
    if (a == NBLK - 1) {
      __hip_atomic_store(cnt, 0u, __ATOMIC_RELAXED, __HIP_MEMORY_SCOPE_AGENT);
      __hip_atomic_store(gen, g + 1u, __ATOMIC_RELEASE, __HIP_MEMORY_SCOPE_AGENT);
    } else {
      while (__hip_atomic_load(gen, __ATOMIC_RELAXED, __HIP_MEMORY_SCOPE_AGENT) == g) {
        __builtin_amdgcn_s_sleep(2);
      }
    }
    __threadfence();
  }
  __syncthreads();
}

__global__ void vader_init(
    const float* __restrict__ eWih, const float* __restrict__ ebih,
    const float* __restrict__ eWhh, const float* __restrict__ ebhh,
    const float* __restrict__ eWch, const float* __restrict__ ebch,
    const float* __restrict__ dbih, const float* __restrict__ dWhh,
    const float* __restrict__ dbhh, const float* __restrict__ dWch,
    const float* __restrict__ dbch, float* __restrict__ ws) {
  const int i0 = blockIdx.x * blockDim.x + threadIdx.x;
  const int stride = gridDim.x * blockDim.x;
  for (int i = i0; i < 4096; i += stride) ws[i] = 0.f;
  for (int i = i0; i < 512 * 256; i += stride) {
    ws[HBUF + i] = 0.f;
    ws[CBUF + i] = 0.f;
  }
  for (int i = i0; i < 1024 * 576; i += stride) {
    int n = i / 576, k = i - n * 576;
    float v;
    if (k < 64)       v = eWih[n * 64 + k];
    else if (k < 320) v = eWhh[n * 256 + (k - 64)];
    else {
      int j = k - 320;
      if (n < 512)      v = eWch[n * 256 + j];
      else if (n < 768) v = 0.f;
      else              v = eWch[(n - 256) * 256 + j];
    }
    ws[WENC + i] = v;
  }
  for (int i = i0; i < 1024 * 512; i += stride) {
    int n = i >> 9, k = i & 511;
    float v;
    if (k < 256) v = dWhh[n * 256 + k];
    else {
      int j = k - 256;
      if (n < 512)      v = dWch[n * 256 + j];
      else if (n < 768) v = 0.f;
      else              v = dWch[(n - 256) * 256 + j];
    }
    ws[WDEC + i] = v;
  }
  for (int i = i0; i < 1024; i += stride) {
    float bce = (i < 512) ? ebch[i] : ((i < 768) ? 0.f : ebch[i - 256]);
    ws[BENC + i] = ebih[i] + ebhh[i] + bce;
    float bcd = (i < 512) ? dbch[i] : ((i < 768) ? 0.f : dbch[i - 256]);
    ws[BDEC + i] = dbih[i] + dbhh[i] + bcd;
  }
}

__global__ __launch_bounds__(NTHR, 2) void vader_main(
    const float* __restrict__ X, const float* __restrict__ MM, const float* __restrict__ NZ,
    const float* __restrict__ Wimp,
    const float* __restrict__ aeW, const float* __restrict__ aeb,
    const float* __restrict__ adW, const float* __restrict__ adb,
    const float* __restrict__ muW, const float* __restrict__ mub,
    const float* __restrict__ stW, const float* __restrict__ stb,
    const float* __restrict__ oW, const float* __restrict__ ob,
    const float* __restrict__ mcu, const float* __restrict__ vcu, const float* __restrict__ pcu,
    float* __restrict__ ws, float* __restrict__ out) {
  const int bid = blockIdx.x, tid = threadIdx.x;
  const int mi = bid & 7, hi = bid >> 3;
  const int m_base = mi << 6;
  const int hbase = hi << 3;
  // Row ownership permuted so a block's "own" rows lie in its OWN M-tile:
  // b0 = 64*mi + 2*hi (bijective over bid). Required for group-local barriers:
  // every cross-block dependency (h/c/ximp rows m_base..m_base+63) is then
  // produced and consumed entirely within the 32-block group sharing mi.
  const int b0 = m_base + (hi << 1);

  // ---- LDS ----
  __shared__ __align__(16) float In_s[2][64][68];
  __shared__ __align__(16) float W_s[32][576];       // 73.7 KB resident gate-weight slice
  __shared__ __align__(16) char u1_raw[17408];       // enc: WimpT | dec: Wo_s + Xm/Mm
  __shared__ __align__(16) char u2_raw[8192];        // GateS | heads arrays | red_s
  __shared__ float C_s[64][9];
  __shared__ float Xrow_s[2][64], Mrow_s[2][64];
  __shared__ float lat_s[2][3];
  __shared__ float tot_s[5];

  float (*WimpT_s)[68] = (float(*)[68])u1_raw;
  float (*Wo_s)[260]   = (float(*)[260])u1_raw;
  float (*Xm_s)[12]    = (float(*)[12])(u1_raw + 8320);
  float (*Mm_s)[12]    = (float(*)[12])(u1_raw + 8320 + 3072);
  float* GateS         = (float*)u2_raw;
  float (*Hrow_s)[256] = (float(*)[256])u2_raw;
  float (*cc_s)[256]   = (float(*)[256])(u2_raw + 2048);
  float (*mu_s)[32]    = (float(*)[32])(u2_raw + 4096);
  float (*std_s)[32]   = (float(*)[32])(u2_raw + 4352);
  float (*z_s)[32]     = (float(*)[32])(u2_raw + 4608);
  float* red_s         = (float*)u2_raw;

  float* hbuf = ws + HBUF;
  float* cbuf = ws + CBUF;
  float* ximp = ws + XIMP;
  float* part = ws + OFF_PART;

  const int mA = tid & 31, nP = tid >> 5;
  const int n0 = nP << 1, n1 = n0 + 1;
  const int N0 = ((n0 >> 3) << 8) + hbase + (n0 & 7);
  const int N1 = ((n1 >> 3) << 8) + hbase + (n1 & 7);
  const int st_r = tid >> 3, st_c4 = tid & 7;
  const int mX = tid & 63, dX = tid >> 6;
  const int um = tid >> 3, uh = tid & 7;
  const bool mse_blk = (hi < 8);

  float ssq_acc = 0.f, msum_acc = 0.f;

  // ---------- helpers ----------
  auto stage_ld = [&](const float* src, int srd, int koff, float4& v0, float4& v1) {
    const float* bp = src + (size_t)(m_base + st_r) * srd + koff + (st_c4 << 2);
    v0 = *(const float4*)bp;
    v1 = *(const float4*)(bp + 32);
  };
  auto stage_wr = [&](int buf, float4 v0, float4 v1) {
    float* q = &In_s[buf][st_r][st_c4 << 2];
    *(float4*)q = v0;
    *(float4*)(q + 32) = v1;
  };
  auto chunk_src_enc = [&](int ch, int t, int pp, const float*& src, int& srd, int& koff) {
    if (ch == 0)      { src = ximp + (size_t)(t & 1) * (512 * 64); srd = 64;  koff = 0; }
    else if (ch < 5)  { src = hbuf + (size_t)pp * SZ; srd = 256; koff = (ch - 1) << 6; }
    else              { src = cbuf + (size_t)pp * SZ; srd = 256; koff = (ch - 5) << 6; }
  };
  auto chunk_src_dec = [&](int ch, int pp, const float*& src, int& srd, int& koff) {
    if (ch < 4) { src = hbuf + (size_t)pp * SZ; srd = 256; koff = ch << 6; }
    else        { src = cbuf + (size_t)pp * SZ; srd = 256; koff = (ch - 4) << 6; }
  };
  auto gates_chunk = [&](int buf, int ch, float& a00, float& a01, float& a10, float& a11) {
    const float* w0p = &W_s[n0][ch << 6];
    const float* w1p = &W_s[n1][ch << 6];
#pragma unroll
    for (int k4 = 0; k4 < 16; ++k4) {
      float4 w0 = *(const float4*)(w0p + (k4 << 2));
      float4 w1 = *(const float4*)(w1p + (k4 << 2));
      float4 a0 = *(const float4*)&In_s[buf][mA][k4 << 2];
      float4 a1 = *(const float4*)&In_s[buf][mA + 32][k4 << 2];
      a00 = fmaf(a0.x, w0.x, a00); a00 = fmaf(a0.y, w0.y, a00);
      a00 = fmaf(a0.z, w0.z, a00); a00 = fmaf(a0.w, w0.w, a00);
      a01 = fmaf(a0.x, w1.x, a01); a01 = fmaf(a0.y, w1.y, a01);
      a01 = fmaf(a0.z, w1.z, a01); a01 = fmaf(a0.w, w1.w, a01);
      a10 = fmaf(a1.x, w0.x, a10); a10 = fmaf(a1.y, w0.y, a10);
      a10 = fmaf(a1.z, w0.z, a10); a10 = fmaf(a1.w, w0.w, a10);
      a11 = fmaf(a1.x, w1.x, a11); a11 = fmaf(a1.y, w1.y, a11);
      a11 = fmaf(a1.z, w1.z, a11); a11 = fmaf(a1.w, w1.w, a11);
    }
  };
  auto xrec_chunk = [&](int buf, int ch, float& ax) {
    const float* wp = &Wo_s[dX][ch << 6];
#pragma unroll
    for (int k4 = 0; k4 < 16; ++k4) {
      float4 w = *(const float4*)(wp + (k4 << 2));
      float4 av = *(const float4*)&In_s[buf][mX][k4 << 2];
      ax = fmaf(av.x, w.x, ax);
      ax = fmaf(av.y, w.y, ax);
      ax = fmaf(av.z, w.z, ax);
      ax = fmaf(av.w, w.w, ax);
    }
  };
  auto do_update = [&](float a00, float a01, float a10, float a11, float* hbo, float* cbo) {
    GateS[((n0 >> 3) << 9) + (mA << 3) + (n0 & 7)] = a00;
    GateS[((n0 >> 3) << 9) + ((mA + 32) << 3) + (n0 & 7)] = a10;
    GateS[((n1 >> 3) << 9) + (mA << 3) + (n1 & 7)] = a01;
    GateS[((n1 >> 3) << 9) + ((mA + 32) << 3) + (n1 & 7)] = a11;
    __syncthreads();
    float iv = sigm_(GateS[(0 << 9) + (um << 3) + uh]);
    float fv = sigm_(GateS[(1 << 9) + (um << 3) + uh]);
    float gv = tanhf(GateS[(2 << 9) + (um << 3) + uh]);
    float ov = sigm_(GateS[(3 << 9) + (um << 3) + uh]);
    float cold = C_s[um][uh];
    float cn = fmaf(fv, cold, iv * gv);
    float hn = ov * tanhf(cn);
    C_s[um][uh] = cn;
    size_t off = (size_t)(m_base + um) * 256 + hbase + uh;
    hbo[off] = hn;
    cbo[off] = cn;
  };
  auto produce_ximp = [&](int tn) {
    if (tid < 128) {
      int r = tid >> 6, d = tid & 63;
      Xrow_s[r][d] = X[((size_t)(b0 + r) * 256 + tn) * 64 + d];
    } else if (tid < 256) {
      int r = (tid >> 6) & 1, d = tid & 63;
      Mrow_s[r][d] = MM[((size_t)(b0 + r) * 256 + tn) * 64 + d];
    }
    __syncthreads();
    if (tid < 128) {
      int r = tid >> 6, d = tid & 63;
      float s = 0.f;
#pragma unroll 8
      for (int e = 0; e < 64; ++e) s = fmaf(Xrow_s[r][e], WimpT_s[e][d], s);
      float x = Xrow_s[r][d];
      ximp[(size_t)(tn & 1) * (512 * 64) + (size_t)(b0 + r) * 64 + d] =
          fmaf(x, Mrow_s[r][d], s * (1.f - x));
    }
  };

  // ---------- encoder phase setup ----------
  {
    int n = tid >> 4, c16 = tid & 15;
    const float* wsrc = ws + WENC + (size_t)(((n >> 3) << 8) + hbase + (n & 7)) * 576;
#pragma unroll
    for (int j = 0; j < 9; ++j) {
      int c4 = c16 * 9 + j;
      *(float4*)&W_s[n][c4 << 2] = *(const float4*)&wsrc[c4 << 2];
    }
    for (int i = tid; i < 4096; i += NTHR) {
      int d = i >> 6, e = i & 63;
      WimpT_s[e][d] = Wimp[i];
    }
    for (int i = tid; i < 576; i += NTHR) ((float*)C_s)[i] = 0.f;
  }
  float bia0 = ws[BENC + N0], bia1 = ws[BENC + N1];
  produce_ximp(0);
  gbar_g(ws, mi);

  // ---------- encoder scan ----------
  int p = 0;
  for (int t = 0; t < 256; ++t) {
    float a00 = bia0, a01 = bia1, a10 = bia0, a11 = bia1;
    float4 r0, r1;
    const float* src; int srd, koff;
    chunk_src_enc(0, t, p, src, srd, koff);
    stage_ld(src, srd, koff, r0, r1);
    stage_wr(0, r0, r1);
    __syncthreads();
    for (int ch = 0; ch < 9; ++ch) {
      if (ch < 8) { chunk_src_enc(ch + 1, t, p, src, srd, koff); stage_ld(src, srd, koff, r0, r1); }
      gates_chunk(ch & 1, ch, a00, a01, a10, a11);
      if (ch < 8) stage_wr((ch + 1) & 1, r0, r1);
      __syncthreads();
    }
    do_update(a00, a01, a10, a11, hbuf + (size_t)(p ^ 1) * SZ, cbuf + (size_t)(p ^ 1) * SZ);
    if (t < 255) produce_ximp(t + 1);
    gbar_g(ws, mi);
    p ^= 1;
  }
  // p == 0, c_T lives in cbuf[0]

  // ---------- AE heads + latent (own rows b0, b0+1) ----------
  {
    int rr = tid >> 8, j = tid & 255;
    Hrow_s[rr][j] = cbuf[(size_t)(b0 + rr) * 256 + j];
  }
  __syncthreads();
  {
    int rr = tid >> 8, u = tid & 255;
    float a = aeb[u];
    const float4* wr = (const float4*)(aeW + (size_t)u * 256);
#pragma unroll 4
    for (int j4 = 0; j4 < 64; ++j4) {
      float4 w = wr[j4];
      a = fmaf(Hrow_s[rr][(j4 << 2) + 0], w.x, a);
      a = fmaf(Hrow_s[rr][(j4 << 2) + 1], w.y, a);
      a = fmaf(Hrow_s[rr][(j4 << 2) + 2], w.z, a);
      a = fmaf(Hrow_s[rr][(j4 << 2) + 3], w.w, a);
    }
    cc_s[rr][u] = softplus_(a);
  }
  __syncthreads();
  if (tid < 128) {
    int rr = tid >> 6, sel = (tid >> 5) & 1, q = tid & 31;
    const float* Wm = sel ? stW : muW;
    float a = sel ? stb[q] : mub[q];
    const float4* wr = (const float4*)(Wm + (size_t)q * 256);
#pragma unroll 4
    for (int j4 = 0; j4 < 64; ++j4) {
      float4 w = wr[j4];
      a = fmaf(cc_s[rr][(j4 << 2) + 0], w.x, a);
      a = fmaf(cc_s[rr][(j4 << 2) + 1], w.y, a);
      a = fmaf(cc_s[rr][(j4 << 2) + 2], w.z, a);
      a = fmaf(cc_s[rr][(j4 << 2) + 3], w.w, a);
    }
    if (sel) std_s[rr][q] = a; else mu_s[rr][q] = a;
  }
  __syncthreads();
  if (tid < 64) {
    int rr = tid >> 5, q = tid & 31;
    float zv = fmaf(expf(0.5f * std_s[rr][q]), NZ[(size_t)(b0 + rr) * 32 + q], mu_s[rr][q]);
    z_s[rr][q] = zv;
    out[1 + (size_t)(b0 + rr) * 32 + q] = zv;
  }
  __syncthreads();
  {
    int rr = tid >> 8, u = tid & 255;
    float a = adb[u];
#pragma unroll
    for (int q = 0; q < 32; ++q) a = fmaf(z_s[rr][q], adW[(size_t)u * 32 + q], a);
    hbuf[(size_t)(b0 + rr) * 256 + u] = softplus_(a);
    cbuf[(size_t)(b0 + rr) * 256 + u] = 0.f;
  }
  if (tid < 128) {
    int wv = tid >> 6, ln = tid & 63;
    if (ln < 32) {
      float zd = z_s[wv][ln], mud = mu_s[wv][ln], sdd = std_s[wv][ln];
      float vt = expf(sdd);
      float l3p = -0.5f * (1.f + sdd);
      float lp[8], tk[8];
#pragma unroll
      for (int k = 0; k < 8; ++k) {
        float vc = softplus_(vcu[(k << 5) + ln]);
        float lvc = logf(vc + EPSF);
        float mc = mcu[(k << 5) + ln];
        float dz = zd - mc;
        float a_d = lvc + LOG2PIF + dz * dz / vc;
        float ive = 1.f / (vc + EPSF);
        float dm = mud - mc;
        float t_d = lvc + fmaf(vt, ive, dm * dm * ive);
#pragma unroll
        for (int off = 16; off > 0; off >>= 1) {
          a_d += __shfl_xor(a_d, off, 64);
          t_d += __shfl_xor(t_d, off, 64);
        }
        lp[k] = -0.5f * a_d;
        tk[k] = t_d;
      }
#pragma unroll
      for (int off = 16; off > 0; off >>= 1) l3p += __shfl_xor(l3p, off, 64);
      float phv[8], mx = -1e30f;
#pragma unroll
      for (int k = 0; k < 8; ++k) { phv[k] = pcu[k]; mx = fmaxf(mx, phv[k]); }
      float se = 0.f;
#pragma unroll
      for (int k = 0; k < 8; ++k) se += expf(phv[k] - mx);
      float lphi[8], lpf[8], mx2 = -1e30f;
#pragma unroll
      for (int k = 0; k < 8; ++k) {
        lphi[k] = logf(expf(phv[k] - mx) / se + EPSF);
        lpf[k] = lphi[k] + lp[k];
        mx2 = fmaxf(mx2, lpf[k]);
      }
      float s2 = 0.f;
#pragma unroll
      for (int k = 0; k < 8; ++k) s2 += expf(lpf[k] - mx2);
      float lse = mx2 + logf(s2);
      float l1 = 0.f, l2 = 0.f;
#pragma unroll
      for (int k = 0; k < 8; ++k) {
        float lg = lpf[k] - lse;
        float gm = expf(lg);
        l1 = fmaf(gm, tk[k], l1);
        l2 = fmaf(gm, lphi[k] - lg, l2);
      }
      if (ln == 0) {
        lat_s[wv][0] = 0.5f * l1;
        lat_s[wv][1] = -l2;
        lat_s[wv][2] = l3p;
      }
    }
  }
  __syncthreads();

  // ---------- decoder phase setup ----------
  {
    int n = tid >> 4, c16 = tid & 15;
    const float* wsrc = ws + WDEC + (size_t)(((n >> 3) << 8) + hbase + (n & 7)) * 512;
#pragma unroll
    for (int j = 0; j < 8; ++j) {
      int c4 = (c16 << 3) + j;
      *(float4*)&W_s[n][c4 << 2] = *(const float4*)&wsrc[c4 << 2];
    }
    if (mse_blk) {
      int r = tid >> 6, c4 = tid & 63;
      *(float4*)&Wo_s[r][c4 << 2] = *(const float4*)&oW[(size_t)((hi << 3) + r) * 256 + (c4 << 2)];
    }
    for (int i = tid; i < 576; i += NTHR) ((float*)C_s)[i] = 0.f;
  }
  float bia0d = ws[BDEC + N0], bia1d = ws[BDEC + N1];
  float obv = mse_blk ? ob[(hi << 3) + dX] : 0.f;
  gbar_g(ws, mi);

  // ---------- decoder scan (+ fused X_rec / masked MSE) ----------
  for (int t = 0; t <= 256; ++t) {
    const bool dg = (t < 256);
    const bool dm = mse_blk && (t >= 1);
    const int NC = dg ? 8 : 4;
    float a00 = bia0d, a01 = bia1d, a10 = bia0d, a11 = bia1d;
    float ax = 0.f;
    float4 r0, r1;
    const float* src; int srd, koff;
    chunk_src_dec(0, p, src, srd, koff);
    stage_ld(src, srd, koff, r0, r1);
    stage_wr(0, r0, r1);
    if (dm) {
      if (tid < 128) {
        int r2 = tid >> 1, hf = tid & 1;
        *(float4*)&Xm_s[r2][hf << 2] =
            *(const float4*)&X[((size_t)(m_base + r2) * 256 + (t - 1)) * 64 + (hi << 3) + (hf << 2)];
      } else if (tid < 256) {
        int r2 = (tid - 128) >> 1, hf = tid & 1;
        *(float4*)&Mm_s[r2][hf << 2] =
            *(const float4*)&MM[((size_t)(m_base + r2) * 256 + (t - 1)) * 64 + (hi << 3) + (hf << 2)];
      }
    }
    __syncthreads();
    for (int ch = 0; ch < NC; ++ch) {
      if (ch + 1 < NC) { chunk_src_dec(ch + 1, p, src, srd, koff); stage_ld(src, srd, koff, r0, r1); }
      if (dg) gates_chunk(ch & 1, ch, a00, a01, a10, a11);
      if (dm && ch < 4) xrec_chunk(ch & 1, ch, ax);
      if (ch + 1 < NC) stage_wr((ch + 1) & 1, r0, r1);
      __syncthreads();
    }
    if (dm) {
      float xr = ax + obv;
      float df = xr - Xm_s[mX][dX];
      float mv = Mm_s[mX][dX];
      ssq_acc = fmaf(mv, df * df, ssq_acc);
      msum_acc += mv;
    }
    if (dg) {
      do_update(a00, a01, a10, a11, hbuf + (size_t)(p ^ 1) * SZ, cbuf + (size_t)(p ^ 1) * SZ);
      gbar_g(ws, mi);
      p ^= 1;
    }
  }

  // ---------- per-block partials ----------
  red_s[tid] = ssq_acc;
  __syncthreads();
  for (int s = 256; s > 0; s >>= 1) { if (tid < s) red_s[tid] += red_s[tid + s]; __syncthreads(); }
  if (tid == 0) part[(bid << 3) + 0] = red_s[0];
  __syncthreads();
  red_s[tid] = msum_acc;
  __syncthreads();
  for (int s = 256; s > 0; s >>= 1) { if (tid < s) red_s[tid] += red_s[tid + s]; __syncthreads(); }
  if (tid == 0) {
    part[(bid << 3) + 1] = red_s[0];
    part[(bid << 3) + 2] = lat_s[0][0] + lat_s[1][0];
    part[(bid << 3) + 3] = lat_s[0][1] + lat_s[1][1];
    part[(bid << 3) + 4] = lat_s[0][2] + lat_s[1][2];
  }
  gbar_full(ws);

  // ---------- final reduce + loss (block 0) ----------
  if (bid == 0) {
    for (int c = 0; c < 5; ++c) {
      red_s[tid] = (tid < 256) ? part[(tid << 3) + c] : 0.f;
      __syncthreads();
      for (int s = 256; s > 0; s >>= 1) { if (tid < s) red_s[tid] += red_s[tid + s]; __syncthreads(); }
      if (tid == 0) tot_s[c] = red_s[0];
      __syncthreads();
    }
    if (tid == 0) {
      float ssq = tot_s[0], msum = tot_s[1];
      float mse = ssq / (msum + 1e-12f);
      float recon = mse * 16384.f / msum;
      float latent = (tot_s[2] + tot_s[3] + tot_s[4]) / 512.f;
      out[0] = recon + latent;
    }
  }
}

extern "C" void kernel_launch(void* const* d_in, const int* in_sizes, int n_in,
                              void* d_out, int out_size, void* d_ws, size_t ws_size,
                              hipStream_t stream) {
  (void)in_sizes; (void)out_size;
  if (n_in < 29) return;
  if (ws_size < WS_NEED * sizeof(float)) return;
  const float* X    = (const float*)d_in[0];
  const float* MM   = (const float*)d_in[1];
  const float* NZ   = (const float*)d_in[2];
  const float* Wimp = (const float*)d_in[3];
  const float* eWih = (const float*)d_in[4];
  const float* ebih = (const float*)d_in[5];
  const float* eWhh = (const float*)d_in[6];
  const float* ebhh = (const float*)d_in[7];
  const float* eWch = (const float*)d_in[8];
  const float* ebch = (const float*)d_in[9];
  const float* dbih = (const float*)d_in[11];
  const float* dWhh = (const float*)d_in[12];
  const float* dbhh = (const float*)d_in[13];
  const float* dWch = (const float*)d_in[14];
  const float* dbch = (const float*)d_in[15];
  const float* aeW  = (const float*)d_in[16];
  const float* aeb  = (const float*)d_in[17];
  const float* adW  = (const float*)d_in[18];
  const float* adb  = (const float*)d_in[19];
  const float* muW  = (const float*)d_in[20];
  const float* mub  = (const float*)d_in[21];
  const float* stW  = (const float*)d_in[22];
  const float* stb  = (const float*)d_in[23];
  const float* oW   = (const float*)d_in[24];
  const float* ob   = (const float*)d_in[25];
  const float* mcu  = (const float*)d_in[26];
  const float* vcu  = (const float*)d_in[27];
  const float* pcu  = (const float*)d_in[28];
  float* ws = (float*)d_ws;

  vader_init<<<512, 256, 0, stream>>>(eWih, ebih, eWhh, ebhh, eWch, ebch,
                                      dbih, dWhh, dbhh, dWch, dbch, ws);
  vader_main<<<NBLK, NTHR, 0, stream>>>(X, MM, NZ, Wimp, aeW, aeb, adW, adb,
                                        muW, mub, stW, stb, oW, ob, mcu, vcu, pcu,
                                        ws, (float*)d_out);
}